// Round 10
// baseline (1066.571 us; speedup 1.0000x reference)
//
#include <hip/hip_runtime.h>

#define NN 100000
#define NE 1600000
#define SCAN_B 98   // 98*1024 >= NN
#define NB 782      // buckets of 128 nodes: 782*128 >= NN
#define SUBCAP 512  // per (bucket,xcd) capacity; mean 256, 512 ~ +16 sigma
#define MAXB 4096   // 8*SUBCAP — guaranteed LDS bound

typedef _Float16 half8 __attribute__((ext_vector_type(8)));
typedef float f32x4 __attribute__((ext_vector_type(4)));
struct h2s { _Float16 x, y; };
struct h4s { _Float16 a, b, c, d; };

static __device__ __forceinline__ void unpack_pair(long pv, int& s, float& w) {
  s = (int)(unsigned int)(pv & 0xffffffffL);
  int wi = (int)(pv >> 32);
  __builtin_memcpy(&w, &wi, 4);
}

// ---------------- graph prep ----------------
__global__ void k_deg(const int* __restrict__ col, int* __restrict__ degi) {
  int e = blockIdx.x * blockDim.x + threadIdx.x;
  if (e < NE) atomicAdd(&degi[col[e]], 1);
}

__global__ void k_dis(const int* __restrict__ degi, float* __restrict__ dis) {
  int i = blockIdx.x * blockDim.x + threadIdx.x;
  if (i < NN) {
    int d = degi[i];
    dis[i] = d > 0 ? rsqrtf((float)d) : 0.0f;
  }
}

__global__ void k_scan1(const int* __restrict__ degi, int* __restrict__ bsum) {
  __shared__ int red[256];
  int t = threadIdx.x;
  int base = blockIdx.x * 1024 + t * 4;
  int s = 0;
#pragma unroll
  for (int u = 0; u < 4; ++u) {
    int i = base + u;
    if (i < NN) s += degi[i];
  }
  red[t] = s;
  __syncthreads();
  for (int o = 128; o; o >>= 1) {
    if (t < o) red[t] += red[t + o];
    __syncthreads();
  }
  if (t == 0) bsum[blockIdx.x] = red[0];
}

__global__ void k_scan2(const int* __restrict__ bsum, int* __restrict__ boff,
                        int* __restrict__ off) {
  __shared__ int sh[128];
  int t = threadIdx.x;  // 128
  int v = (t < SCAN_B) ? bsum[t] : 0;
  sh[t] = v;
  __syncthreads();
  for (int o = 1; o < 128; o <<= 1) {
    int u = (t >= o) ? sh[t - o] : 0;
    __syncthreads();
    sh[t] += u;
    __syncthreads();
  }
  if (t < SCAN_B) boff[t] = sh[t] - v;
  if (t == 127) off[NN] = sh[127];
}

__global__ void k_scan3(const int* __restrict__ degi, const int* __restrict__ boff,
                        int* __restrict__ off) {
  __shared__ int red[256];
  int t = threadIdx.x;
  int base = blockIdx.x * 1024 + t * 4;
  int d[4];
  int s = 0;
#pragma unroll
  for (int u = 0; u < 4; ++u) {
    int i = base + u;
    d[u] = (i < NN) ? degi[i] : 0;
    s += d[u];
  }
  red[t] = s;
  __syncthreads();
  for (int o = 1; o < 256; o <<= 1) {
    int u2 = (t >= o) ? red[t - o] : 0;
    __syncthreads();
    red[t] += u2;
    __syncthreads();
  }
  int pre = red[t] - s + boff[blockIdx.x];
#pragma unroll
  for (int u = 0; u < 4; ++u) {
    int i = base + u;
    if (i < NN) {
      off[i] = pre;
      pre += d[u];
    }
  }
}

// Phase B: scatter packed {row, col&127} into per-(bucket,XCD) sub-buckets.
__global__ void k_bscatter(const int* __restrict__ row, const int* __restrict__ col,
                           int* __restrict__ bcur, unsigned* __restrict__ pk2) {
  int e = blockIdx.x * blockDim.x + threadIdx.x;
  int x = blockIdx.x & 7;
  if (e < NE) {
    int c = col[e];
    int cell = ((c >> 7) << 3) | x;
    int slot = atomicAdd(&bcur[cell * 16], 1);
    slot = min(slot, SUBCAP - 1);  // statistically unreachable (16 sigma)
    unsigned v = (unsigned)row[e] | ((unsigned)(c & 127) << 17);
    __builtin_nontemporal_store(v, &pk2[(size_t)cell * SUBCAP + slot]);
  }
}

// Phase C: per-bucket LDS counting sort over 8 sub-segments -> sequential E records
__global__ __launch_bounds__(256) void k_bsort(const unsigned* __restrict__ pk2,
                                               const int* __restrict__ bcur,
                                               const int* __restrict__ off,
                                               const float* __restrict__ dis,
                                               long* __restrict__ E) {
  __shared__ unsigned epk[MAXB];
  __shared__ int cnt[128];
  __shared__ int sc[128];
  __shared__ int cur[128];
  __shared__ float sdis[128];
  __shared__ int soff[9];
  int b = blockIdx.x;
  int n0 = b << 7;
  int gb = off[n0];
  int t = threadIdx.x;
  if (t == 0) {
    int acc = 0;
#pragma unroll
    for (int x = 0; x < 8; ++x) {
      soff[x] = acc;
      acc += min(bcur[((b << 3) | x) * 16], SUBCAP);
    }
    soff[8] = acc;
  }
  if (t < 128) {
    cnt[t] = 0;
    sdis[t] = (n0 + t < NN) ? dis[n0 + t] : 0.f;
  }
  __syncthreads();
  int m = soff[8];
#pragma unroll
  for (int x = 0; x < 8; ++x) {
    int c0 = soff[x], c1 = soff[x + 1];
    const unsigned* seg = &pk2[(size_t)((b << 3) | x) * SUBCAP];
    for (int i = c0 + t; i < c1; i += 256) epk[i] = seg[i - c0];
  }
  __syncthreads();
  for (int i = t; i < m; i += 256) atomicAdd(&cnt[epk[i] >> 17], 1);
  __syncthreads();
  if (t < 128) sc[t] = cnt[t];
  __syncthreads();
  for (int o = 1; o < 128; o <<= 1) {
    int u = (t < 128 && t >= o) ? sc[t - o] : 0;
    __syncthreads();
    if (t < 128) sc[t] += u;
    __syncthreads();
  }
  if (t < 128) cur[t] = sc[t] - cnt[t];  // exclusive
  __syncthreads();
  for (int i = t; i < m; i += 256) {
    unsigned p = epk[i];
    int c = (int)(p >> 17);
    int r = (int)(p & 0x1FFFFu);
    int pos = gb + atomicAdd(&cur[c], 1);
    float w = dis[r] * sdis[c];
    int wi;
    __builtin_memcpy(&wi, &w, 4);
    E[pos] = (long)(unsigned int)r | ((long)wi << 32);
  }
}

// convert+transpose conv weights: cw [12][128k][128n] f32 -> wt [12][128n][128k] f16
__global__ void k_wprep(const float* __restrict__ cw, _Float16* __restrict__ wt) {
  int i = blockIdx.x * 256 + threadIdx.x;
  if (i < 12 * 16384) {
    int mat = i >> 14;
    int rem = i & 16383;
    int k = rem >> 7;
    int n = rem & 127;
    wt[(mat << 14) | (n << 7) | k] = (_Float16)cw[i];
  }
}

// last layer fold: uvec[s][k] = sum_n W3_s[k][n]*fcw[n]; cval = cb3.fcw + fcb
__global__ void k_uprep(const float* __restrict__ cw, const float* __restrict__ cb,
                        const float* __restrict__ fcw, const float* __restrict__ fcb,
                        float* __restrict__ uvec, float* __restrict__ cval) {
  int i = blockIdx.x * 256 + threadIdx.x;
  if (i < 512) {
    int s = i >> 7, k = i & 127;
    const float* W = cw + (size_t)(8 + s) * 16384 + k * 128;
    float acc = 0.f;
    for (int n = 0; n < 128; ++n) acc += W[n] * fcw[n];
    uvec[i] = acc;
  }
  if (i == 512) {
    float acc = 0.f;
    for (int n = 0; n < 128; ++n) acc += cb[2 * 128 + n] * fcw[n];
    *cval = acc + fcb[0];
  }
}

// ---------------- propagation ----------------
// fp16 16-wide: 8 lanes per node, 8 nodes per 64-thread block; packed E meta
__global__ void k_prop16h(const h2s* __restrict__ h, const int* __restrict__ off,
                          const long* __restrict__ E, h2s* __restrict__ out) {
  int t = threadIdx.x;  // 64
  int node = blockIdx.x * 8 + (t >> 3);
  int f = t & 7;
  int b = off[node], e = off[node + 1];
  float ax = 0.f, ay = 0.f;
  int j = b;
  for (; j + 2 <= e; j += 2) {
    int s0, s1;
    float w0, w1;
    unpack_pair(E[j], s0, w0);
    unpack_pair(E[j + 1], s1, w1);
    h2s v0 = h[s0 * 8 + f];
    h2s v1 = h[s1 * 8 + f];
    ax = fmaf((float)v0.x, w0, fmaf((float)v1.x, w1, ax));
    ay = fmaf((float)v0.y, w0, fmaf((float)v1.y, w1, ay));
  }
  if (j < e) {
    int s;
    float w;
    unpack_pair(E[j], s, w);
    h2s v = h[s * 8 + f];
    ax = fmaf((float)v.x, w, ax);
    ay = fmaf((float)v.y, w, ay);
  }
  h2s o;
  o.x = (_Float16)ax;
  o.y = (_Float16)ay;
  unsigned bits;
  __builtin_memcpy(&bits, &o, 4);
  __builtin_nontemporal_store(bits, (unsigned*)&out[node * 8 + f]);
}

// fp16 128-wide: 256-thr block = 4 waves, one node per wave.
// Meta: lanes' 8-lane groups all load E[j + (t&7)] (one 64B line, ONE instr
// for 8 edges), then __shfl(.,u,8) broadcasts each record wave-wide.
__global__ __launch_bounds__(256) void k_prop128h(const h2s* __restrict__ h,
                                                  const int* __restrict__ off,
                                                  const long* __restrict__ E,
                                                  h2s* __restrict__ out) {
  int node = blockIdx.x * 4 + (threadIdx.x >> 6);
  int t = threadIdx.x & 63;
  int b = off[node], e = off[node + 1];
  float ax = 0.f, ay = 0.f;
  int j = b;
  for (; j + 8 <= e; j += 8) {
    long pv = E[j + (t & 7)];
    h2s v[8];
    float w[8];
#pragma unroll
    for (int u = 0; u < 8; ++u) {
      long p = __shfl(pv, u, 8);
      int s;
      unpack_pair(p, s, w[u]);
      v[u] = h[s * 64 + t];
    }
#pragma unroll
    for (int u = 0; u < 8; ++u) {
      ax = fmaf((float)v[u].x, w[u], ax);
      ay = fmaf((float)v[u].y, w[u], ay);
    }
  }
  for (; j < e; ++j) {
    int s;
    float w;
    unpack_pair(E[j], s, w);
    h2s v = h[s * 64 + t];
    ax = fmaf((float)v.x, w, ax);
    ay = fmaf((float)v.y, w, ay);
  }
  h2s o;
  o.x = (_Float16)ax;
  o.y = (_Float16)ay;
  unsigned bits;
  __builtin_memcpy(&bits, &o, 4);
  __builtin_nontemporal_store(bits, (unsigned*)&out[node * 64 + t]);
}

// ---------------- fused TAG layer GEMM (128->128, 4 sources, MFMA f16) ----------------
template <bool RELU>
__global__ __launch_bounds__(256) void k_tag4_mfma(
    const _Float16* __restrict__ A0, const _Float16* __restrict__ A1,
    const _Float16* __restrict__ A2, const _Float16* __restrict__ A3,
    const _Float16* __restrict__ Wt, const float* __restrict__ bias,
    _Float16* __restrict__ out) {
  __shared__ _Float16 Wl[16384];  // 32 KB
  int tid = threadIdx.x;
  int wid = tid >> 6;
  int lane = tid & 63;
  int r = lane & 15, kg = lane >> 4;
  int m0 = blockIdx.x * 128 + wid * 32;
  int row0 = min(m0 + r, NN - 1);
  int row1 = min(m0 + 16 + r, NN - 1);
  f32x4 acc0[8] = {}, acc1[8] = {};
  const _Float16* As[4] = {A0, A1, A2, A3};
#pragma unroll
  for (int s = 0; s < 4; ++s) {
    const float4* Wg = (const float4*)(Wt + (s << 14));  // 2048 granules of 16B
    __syncthreads();
#pragma unroll
    for (int u = 0; u < 8; ++u) {
      int g = tid + u * 256;
      int sg = g ^ ((g >> 4) & 7);
      *(float4*)((char*)Wl + g * 16) = Wg[sg];
    }
    __syncthreads();
    const _Float16* A = As[s];
    half8 a0[4], a1[4];
#pragma unroll
    for (int kc = 0; kc < 4; ++kc) {
      int kbase = kc * 32 + kg * 8;
      a0[kc] = *(const half8*)&A[(size_t)row0 * 128 + kbase];
      a1[kc] = *(const half8*)&A[(size_t)row1 * 128 + kbase];
    }
#pragma unroll
    for (int kc = 0; kc < 4; ++kc) {
      int kb2 = (kc * 32 + kg * 8) * 2;
#pragma unroll
      for (int nb = 0; nb < 8; ++nb) {
        int n = nb * 16 + r;
        int ba = ((n << 8) + kb2) ^ ((n & 7) << 4);
        half8 b = *(const half8*)((const char*)Wl + ba);
        acc0[nb] = __builtin_amdgcn_mfma_f32_16x16x32_f16(a0[kc], b, acc0[nb], 0, 0, 0);
        acc1[nb] = __builtin_amdgcn_mfma_f32_16x16x32_f16(a1[kc], b, acc1[nb], 0, 0, 0);
      }
    }
  }
  int ccol = lane & 15;
#pragma unroll
  for (int h = 0; h < 2; ++h) {
    int crow0 = m0 + h * 16 + kg * 4;
#pragma unroll
    for (int nb = 0; nb < 8; ++nb) {
      int col = nb * 16 + ccol;
      float bv = bias[col];
      const f32x4& av = h ? acc1[nb] : acc0[nb];
#pragma unroll
      for (int e = 0; e < 4; ++e) {
        float v = av[e] + bv;
        if (RELU) v = fmaxf(v, 0.f);
        int rr = crow0 + e;
        if (rr < NN) out[(size_t)rr * 128 + col] = (_Float16)v;
      }
    }
  }
}

// last layer fused with fc: out[n] = sum_s dot(A_s[n,:], uvec[s]) + cval
__global__ void k_tagfc(const _Float16* __restrict__ A0, const _Float16* __restrict__ A1,
                        const _Float16* __restrict__ A2, const _Float16* __restrict__ A3,
                        const float* __restrict__ uvec, const float* __restrict__ cval,
                        float* __restrict__ out) {
  int node = blockIdx.x;
  int t = threadIdx.x;  // 64, lane t covers feats [2t, 2t+1]
  const h2s* As[4] = {(const h2s*)A0, (const h2s*)A1, (const h2s*)A2, (const h2s*)A3};
  float s = 0.f;
#pragma unroll
  for (int q = 0; q < 4; ++q) {
    h2s v = As[q][(size_t)node * 64 + t];
    float2 u = ((const float2*)(uvec + (q << 7)))[t];
    s = fmaf((float)v.x, u.x, fmaf((float)v.y, u.y, s));
  }
  for (int o = 32; o; o >>= 1) s += __shfl_down(s, o);
  if (t == 0) out[node] = s + *cval;
}

// ---------------- conv0 fused (4 fp16 sources 16-wide -> 128, relu, fp16 out) ----------------
__global__ __launch_bounds__(256) void k_conv0_fused(
    const _Float16* __restrict__ A0, const _Float16* __restrict__ A1,
    const _Float16* __restrict__ A2, const _Float16* __restrict__ A3,
    const float* __restrict__ W /*[4][16][128]*/, const float* __restrict__ bias,
    _Float16* __restrict__ out) {
  __shared__ float Wl[4 * 16 * 128];
  for (int i = threadIdx.x * 4; i < 4 * 16 * 128; i += 1024)
    *(float4*)&Wl[i] = *(const float4*)&W[i];
  __syncthreads();
  int r0 = blockIdx.x * 32 + (threadIdx.x >> 5) * 4;
  int c0 = (threadIdx.x & 31) * 4;
  float acc[4][4] = {};
  const _Float16* As[4] = {A0, A1, A2, A3};
#pragma unroll
  for (int s = 0; s < 4; ++s) {
    const _Float16* A = As[s];
    const float* Ws = &Wl[s * 2048];
#pragma unroll
    for (int k = 0; k < 16; k += 4) {
      float4 w0 = *(const float4*)&Ws[(k + 0) * 128 + c0];
      float4 w1 = *(const float4*)&Ws[(k + 1) * 128 + c0];
      float4 w2 = *(const float4*)&Ws[(k + 2) * 128 + c0];
      float4 w3 = *(const float4*)&Ws[(k + 3) * 128 + c0];
#pragma unroll
      for (int i = 0; i < 4; ++i) {
        h4s a4 = *(const h4s*)&A[(r0 + i) * 16 + k];
        float ax = (float)a4.a, ay = (float)a4.b, az = (float)a4.c, aw = (float)a4.d;
        acc[i][0] = fmaf(ax, w0.x, fmaf(ay, w1.x, fmaf(az, w2.x, fmaf(aw, w3.x, acc[i][0]))));
        acc[i][1] = fmaf(ax, w0.y, fmaf(ay, w1.y, fmaf(az, w2.y, fmaf(aw, w3.y, acc[i][1]))));
        acc[i][2] = fmaf(ax, w0.z, fmaf(ay, w1.z, fmaf(az, w2.z, fmaf(aw, w3.z, acc[i][2]))));
        acc[i][3] = fmaf(ax, w0.w, fmaf(ay, w1.w, fmaf(az, w2.w, fmaf(aw, w3.w, acc[i][3]))));
      }
    }
  }
#pragma unroll
  for (int i = 0; i < 4; ++i) {
    h4s o;
    o.a = (_Float16)fmaxf(acc[i][0] + bias[c0 + 0], 0.f);
    o.b = (_Float16)fmaxf(acc[i][1] + bias[c0 + 1], 0.f);
    o.c = (_Float16)fmaxf(acc[i][2] + bias[c0 + 2], 0.f);
    o.d = (_Float16)fmaxf(acc[i][3] + bias[c0 + 3], 0.f);
    *(h4s*)&out[(size_t)(r0 + i) * 128 + c0] = o;
  }
}

// ---------------- feature embedding GEMM (fp32 in, fp16 out, 16 cols) ----------------
template <int IN, bool ACCUM, bool BIAS>
__global__ void k_mm16h(const float* __restrict__ A, const float* __restrict__ W,
                        const float* __restrict__ bias, _Float16* __restrict__ C) {
  __shared__ float Wl[IN * 16];
  for (int i = threadIdx.x; i < IN * 16; i += 256) Wl[i] = W[i];
  __syncthreads();
  int r = blockIdx.x * 16 + (threadIdx.x >> 4);
  int c = threadIdx.x & 15;
  float acc = 0.f;
  for (int k = 0; k < IN; ++k) acc += A[r * IN + k] * Wl[k * 16 + c];
  int idx = r * 16 + c;
  if (BIAS) acc += bias[c];
  if (ACCUM) acc += (float)C[idx];
  C[idx] = (_Float16)acc;
}

extern "C" void kernel_launch(void* const* d_in, const int* in_sizes, int n_in,
                              void* d_out, int out_size, void* d_ws, size_t ws_size,
                              hipStream_t stream) {
  const float* x = (const float*)d_in[0];
  const int* ei = (const int*)d_in[1];
  const float* fe_ws = (const float*)d_in[2];
  const float* fe_b = (const float*)d_in[3];
  const float* c0_ws = (const float*)d_in[4];
  const float* c0_b = (const float*)d_in[5];
  const float* cw = (const float*)d_in[6];
  const float* cb = (const float*)d_in[7];
  const float* fcw = (const float*)d_in[8];
  const float* fcb = (const float*)d_in[9];
  float* out = (float*)d_out;

  const int* row = ei;
  const int* colv = ei + NE;

  char* wp = (char*)d_ws;
  auto alloc = [&](size_t bytes) {
    char* p = wp;
    wp += (bytes + 511) & ~(size_t)511;
    return p;
  };
  int* degi = (int*)alloc(NN * 4);
  int* off = (int*)alloc((NN + 1) * 4);
  int* bsum = (int*)alloc(SCAN_B * 4);
  int* boff = (int*)alloc(SCAN_B * 4);
  int* bcur = (int*)alloc((size_t)NB * 8 * 16 * 4);
  float* dis = (float*)alloc(NN * 4);
  long* E = (long*)alloc((size_t)NE * 8);
  unsigned* pk2 = (unsigned*)alloc((size_t)NB * 8 * SUBCAP * 4);
  _Float16* wsT = (_Float16*)alloc((size_t)12 * 16384 * 2);
  float* uvec = (float*)alloc(512 * 4);
  float* cval = (float*)alloc(4);
  _Float16* y1h = (_Float16*)alloc((size_t)NN * 16 * 2);
  _Float16* h16 = (_Float16*)alloc((size_t)NN * 16 * 2);
  _Float16* p16b = (_Float16*)alloc((size_t)NN * 16 * 2);
  _Float16* p16c = (_Float16*)alloc((size_t)NN * 16 * 2);
  _Float16* p16d = (_Float16*)alloc((size_t)NN * 16 * 2);
  _Float16* H0 = (_Float16*)alloc((size_t)NN * 128 * 2);
  _Float16* H1 = (_Float16*)alloc((size_t)NN * 128 * 2);
  _Float16* T1 = (_Float16*)alloc((size_t)NN * 128 * 2);
  _Float16* T2 = (_Float16*)alloc((size_t)NN * 128 * 2);
  _Float16* T3 = (_Float16*)alloc((size_t)NN * 128 * 2);

  // ---- graph prep ----
  hipMemsetAsync(degi, 0, NN * 4, stream);
  hipMemsetAsync(bcur, 0, (size_t)NB * 8 * 16 * 4, stream);
  k_deg<<<(NE + 255) / 256, 256, 0, stream>>>(colv, degi);
  k_dis<<<(NN + 255) / 256, 256, 0, stream>>>(degi, dis);
  k_scan1<<<SCAN_B, 256, 0, stream>>>(degi, bsum);
  k_scan2<<<1, 128, 0, stream>>>(bsum, boff, off);
  k_scan3<<<SCAN_B, 256, 0, stream>>>(degi, boff, off);
  k_bscatter<<<(NE + 255) / 256, 256, 0, stream>>>(row, colv, bcur, pk2);
  k_bsort<<<NB, 256, 0, stream>>>(pk2, bcur, off, dis, E);
  k_wprep<<<768, 256, 0, stream>>>(cw, wsT);
  k_uprep<<<3, 256, 0, stream>>>(cw, cb, fcw, fcb, uvec, cval);

  // ---- featureEmbedding: h16 = x@W0 + A(x@W1) + b  (prop commutes with W) ----
  k_mm16h<17, false, false><<<NN / 16, 256, 0, stream>>>(x, fe_ws + 17 * 16, nullptr, y1h);
  k_prop16h<<<NN / 8, 64, 0, stream>>>((const h2s*)y1h, off, E, (h2s*)h16);
  k_mm16h<17, true, true><<<NN / 16, 256, 0, stream>>>(x, fe_ws, fe_b, h16);

  // ---- conv0 (16 -> 128, K=3, relu) -> H0 fp16 ----
  k_prop16h<<<NN / 8, 64, 0, stream>>>((const h2s*)h16, off, E, (h2s*)p16b);
  k_prop16h<<<NN / 8, 64, 0, stream>>>((const h2s*)p16b, off, E, (h2s*)p16c);
  k_prop16h<<<NN / 8, 64, 0, stream>>>((const h2s*)p16c, off, E, (h2s*)p16d);
  k_conv0_fused<<<NN / 32, 256, 0, stream>>>(h16, p16b, p16c, p16d, c0_ws, c0_b, H0);

  // ---- conv1..2 (128 -> 128, K=3): 3 props + fused MFMA GEMM each ----
  _Float16* hin = H0;
  _Float16* hout = H1;
  int mgrid = (NN + 127) / 128;
  int pgrid = NN / 4;  // 4 nodes per 256-thr block
  for (int l = 0; l < 2; ++l) {
    k_prop128h<<<pgrid, 256, 0, stream>>>((const h2s*)hin, off, E, (h2s*)T1);
    k_prop128h<<<pgrid, 256, 0, stream>>>((const h2s*)T1, off, E, (h2s*)T2);
    k_prop128h<<<pgrid, 256, 0, stream>>>((const h2s*)T2, off, E, (h2s*)T3);
    const _Float16* Wl = wsT + (size_t)l * 4 * 16384;
    const float* bl = cb + l * 128;
    k_tag4_mfma<true><<<mgrid, 256, 0, stream>>>(hin, T1, T2, T3, Wl, bl, hout);
    _Float16* t = hin; hin = hout; hout = t;
  }

  // ---- conv3 fused with fc: 3 props + dot against folded weights ----
  k_prop128h<<<pgrid, 256, 0, stream>>>((const h2s*)hin, off, E, (h2s*)T1);
  k_prop128h<<<pgrid, 256, 0, stream>>>((const h2s*)T1, off, E, (h2s*)T2);
  k_prop128h<<<pgrid, 256, 0, stream>>>((const h2s*)T2, off, E, (h2s*)T3);
  k_tagfc<<<NN, 64, 0, stream>>>(hin, T1, T2, T3, uvec, cval, out);
}

// Round 11
// 953.817 us; speedup vs baseline: 1.1182x; 1.1182x over previous
//
#include <hip/hip_runtime.h>

#define NN 100000
#define NE 1600000
#define SCAN_B 98   // 98*1024 >= NN
#define NB 782      // buckets of 128 nodes: 782*128 >= NN
#define SUBCAP 512  // per (bucket,xcd) capacity; mean 256, 512 ~ +16 sigma
#define MAXB 4096   // 8*SUBCAP — guaranteed LDS bound

typedef _Float16 half8 __attribute__((ext_vector_type(8)));
typedef float f32x4 __attribute__((ext_vector_type(4)));
struct h2s { _Float16 x, y; };
struct h4s { _Float16 a, b, c, d; };

// ---------------- graph prep ----------------
__global__ void k_dis(const int* __restrict__ degi, float* __restrict__ dis) {
  int i = blockIdx.x * blockDim.x + threadIdx.x;
  if (i < NN) {
    int d = degi[i];
    dis[i] = d > 0 ? rsqrtf((float)d) : 0.0f;
  }
}

__global__ void k_scan1(const int* __restrict__ degi, int* __restrict__ bsum) {
  __shared__ int red[256];
  int t = threadIdx.x;
  int base = blockIdx.x * 1024 + t * 4;
  int s = 0;
#pragma unroll
  for (int u = 0; u < 4; ++u) {
    int i = base + u;
    if (i < NN) s += degi[i];
  }
  red[t] = s;
  __syncthreads();
  for (int o = 128; o; o >>= 1) {
    if (t < o) red[t] += red[t + o];
    __syncthreads();
  }
  if (t == 0) bsum[blockIdx.x] = red[0];
}

__global__ void k_scan2(const int* __restrict__ bsum, int* __restrict__ boff,
                        int* __restrict__ off) {
  __shared__ int sh[128];
  int t = threadIdx.x;  // 128
  int v = (t < SCAN_B) ? bsum[t] : 0;
  sh[t] = v;
  __syncthreads();
  for (int o = 1; o < 128; o <<= 1) {
    int u = (t >= o) ? sh[t - o] : 0;
    __syncthreads();
    sh[t] += u;
    __syncthreads();
  }
  if (t < SCAN_B) boff[t] = sh[t] - v;
  if (t == 127) off[NN] = sh[127];
}

__global__ void k_scan3(const int* __restrict__ degi, const int* __restrict__ boff,
                        int* __restrict__ off) {
  __shared__ int red[256];
  int t = threadIdx.x;
  int base = blockIdx.x * 1024 + t * 4;
  int d[4];
  int s = 0;
#pragma unroll
  for (int u = 0; u < 4; ++u) {
    int i = base + u;
    d[u] = (i < NN) ? degi[i] : 0;
    s += d[u];
  }
  red[t] = s;
  __syncthreads();
  for (int o = 1; o < 256; o <<= 1) {
    int u2 = (t >= o) ? red[t - o] : 0;
    __syncthreads();
    red[t] += u2;
    __syncthreads();
  }
  int pre = red[t] - s + boff[blockIdx.x];
#pragma unroll
  for (int u = 0; u < 4; ++u) {
    int i = base + u;
    if (i < NN) {
      off[i] = pre;
      pre += d[u];
    }
  }
}

// Phase B: scatter packed {row, col&127} into per-(bucket,XCD) sub-buckets.
// x = blockIdx & 7 tracks round-robin block->XCD so each cell's write front is
// exclusive to one XCD L2. Also builds the degree histogram (merged k_deg).
__global__ void k_bscatter(const int* __restrict__ row, const int* __restrict__ col,
                           int* __restrict__ degi, int* __restrict__ bcur,
                           unsigned* __restrict__ pk2) {
  int e = blockIdx.x * blockDim.x + threadIdx.x;
  int x = blockIdx.x & 7;
  if (e < NE) {
    int c = col[e];
    atomicAdd(&degi[c], 1);
    int cell = ((c >> 7) << 3) | x;
    int slot = atomicAdd(&bcur[cell * 16], 1);
    slot = min(slot, SUBCAP - 1);  // statistically unreachable (16 sigma)
    pk2[(size_t)cell * SUBCAP + slot] = (unsigned)row[e] | ((unsigned)(c & 127) << 17);
  }
}

// Phase C: per-bucket LDS counting sort over 8 sub-segments -> sequential src+wh
__global__ __launch_bounds__(256) void k_bsort(const unsigned* __restrict__ pk2,
                                               const int* __restrict__ bcur,
                                               const int* __restrict__ off,
                                               const float* __restrict__ dis,
                                               int* __restrict__ src,
                                               _Float16* __restrict__ wh) {
  __shared__ unsigned epk[MAXB];
  __shared__ int cnt[128];
  __shared__ int sc[128];
  __shared__ int cur[128];
  __shared__ float sdis[128];
  __shared__ int soff[9];
  int b = blockIdx.x;
  int n0 = b << 7;
  int gb = off[n0];
  int t = threadIdx.x;
  if (t == 0) {
    int acc = 0;
#pragma unroll
    for (int x = 0; x < 8; ++x) {
      soff[x] = acc;
      acc += min(bcur[((b << 3) | x) * 16], SUBCAP);
    }
    soff[8] = acc;
  }
  if (t < 128) {
    cnt[t] = 0;
    sdis[t] = (n0 + t < NN) ? dis[n0 + t] : 0.f;
  }
  __syncthreads();
  int m = soff[8];
#pragma unroll
  for (int x = 0; x < 8; ++x) {
    int c0 = soff[x], c1 = soff[x + 1];
    const unsigned* seg = &pk2[(size_t)((b << 3) | x) * SUBCAP];
    for (int i = c0 + t; i < c1; i += 256) epk[i] = seg[i - c0];
  }
  __syncthreads();
  for (int i = t; i < m; i += 256) atomicAdd(&cnt[epk[i] >> 17], 1);
  __syncthreads();
  if (t < 128) sc[t] = cnt[t];
  __syncthreads();
  for (int o = 1; o < 128; o <<= 1) {
    int u = (t < 128 && t >= o) ? sc[t - o] : 0;
    __syncthreads();
    if (t < 128) sc[t] += u;
    __syncthreads();
  }
  if (t < 128) cur[t] = sc[t] - cnt[t];  // exclusive
  __syncthreads();
  for (int i = t; i < m; i += 256) {
    unsigned p = epk[i];
    int c = (int)(p >> 17);
    int r = (int)(p & 0x1FFFFu);
    int pos = gb + atomicAdd(&cur[c], 1);
    src[pos] = r;
    wh[pos] = (_Float16)(dis[r] * sdis[c]);
  }
}

// convert+transpose conv weights: cw [12][128k][128n] f32 -> wt [12][128n][128k] f16
__global__ void k_wprep(const float* __restrict__ cw, _Float16* __restrict__ wt) {
  int i = blockIdx.x * 256 + threadIdx.x;
  if (i < 12 * 16384) {
    int mat = i >> 14;
    int rem = i & 16383;
    int k = rem >> 7;
    int n = rem & 127;
    wt[(mat << 14) | (n << 7) | k] = (_Float16)cw[i];
  }
}

// last layer fold: uvec[s][k] = sum_n W3_s[k][n]*fcw[n]; cval = cb3.fcw + fcb
__global__ void k_uprep(const float* __restrict__ cw, const float* __restrict__ cb,
                        const float* __restrict__ fcw, const float* __restrict__ fcb,
                        float* __restrict__ uvec, float* __restrict__ cval) {
  int i = blockIdx.x * 256 + threadIdx.x;
  if (i < 512) {
    int s = i >> 7, k = i & 127;
    const float* W = cw + (size_t)(8 + s) * 16384 + k * 128;
    float acc = 0.f;
    for (int n = 0; n < 128; ++n) acc += W[n] * fcw[n];
    uvec[i] = acc;
  }
  if (i == 512) {
    float acc = 0.f;
    for (int n = 0; n < 128; ++n) acc += cb[2 * 128 + n] * fcw[n];
    *cval = acc + fcb[0];
  }
}

// ---------------- propagation ----------------
// fp16 16-wide: 8 lanes per node, 8 nodes per 64-thread block (3.2MB, L2-friendly)
__global__ void k_prop16h(const h2s* __restrict__ h, const int* __restrict__ off,
                          const int* __restrict__ src, const _Float16* __restrict__ wh,
                          h2s* __restrict__ out) {
  int t = threadIdx.x;  // 64
  int node = blockIdx.x * 8 + (t >> 3);
  int f = t & 7;
  int b = off[node], e = off[node + 1];
  float ax = 0.f, ay = 0.f;
  int j = b;
  for (; j + 2 <= e; j += 2) {
    int s0 = src[j], s1 = src[j + 1];
    float w0 = (float)wh[j], w1 = (float)wh[j + 1];
    h2s v0 = h[s0 * 8 + f];
    h2s v1 = h[s1 * 8 + f];
    ax = fmaf((float)v0.x, w0, fmaf((float)v1.x, w1, ax));
    ay = fmaf((float)v0.y, w0, fmaf((float)v1.y, w1, ay));
  }
  if (j < e) {
    int s = src[j];
    float w = (float)wh[j];
    h2s v = h[s * 8 + f];
    ax = fmaf((float)v.x, w, ax);
    ay = fmaf((float)v.y, w, ay);
  }
  h2s o;
  o.x = (_Float16)ax;
  o.y = (_Float16)ay;
  unsigned bits;
  __builtin_memcpy(&bits, &o, 4);
  __builtin_nontemporal_store(bits, (unsigned*)&out[node * 8 + f]);
}

// fp16 128-wide contiguous: one node per WAVE (node wave-uniform so src/wh
// metadata stays on the scalar-load path), 2 waves per 128-thr block.
__global__ __launch_bounds__(128) void k_prop128h(const h2s* __restrict__ h,
                                                  const int* __restrict__ off,
                                                  const int* __restrict__ src,
                                                  const _Float16* __restrict__ wh,
                                                  h2s* __restrict__ out) {
  int wid = __builtin_amdgcn_readfirstlane(threadIdx.x >> 6);
  int node = blockIdx.x * 2 + wid;
  int t = threadIdx.x & 63;
  int b = off[node], e = off[node + 1];
  float ax = 0.f, ay = 0.f;
  int j = b;
  for (; j + 8 <= e; j += 8) {
    h2s v[8];
    float w[8];
#pragma unroll
    for (int u = 0; u < 8; ++u) {
      v[u] = h[src[j + u] * 64 + t];
      w[u] = (float)wh[j + u];
    }
#pragma unroll
    for (int u = 0; u < 8; ++u) {
      ax = fmaf((float)v[u].x, w[u], ax);
      ay = fmaf((float)v[u].y, w[u], ay);
    }
  }
  for (; j < e; ++j) {
    int s = src[j];
    float w = (float)wh[j];
    h2s v = h[s * 64 + t];
    ax = fmaf((float)v.x, w, ax);
    ay = fmaf((float)v.y, w, ay);
  }
  h2s o;
  o.x = (_Float16)ax;
  o.y = (_Float16)ay;
  unsigned bits;
  __builtin_memcpy(&bits, &o, 4);
  __builtin_nontemporal_store(bits, (unsigned*)&out[node * 64 + t]);
}

// ---------------- fused TAG layer GEMM (128->128, 4 sources, MFMA f16) ----------------
template <bool RELU>
__global__ __launch_bounds__(256) void k_tag4_mfma(
    const _Float16* __restrict__ A0, const _Float16* __restrict__ A1,
    const _Float16* __restrict__ A2, const _Float16* __restrict__ A3,
    const _Float16* __restrict__ Wt, const float* __restrict__ bias,
    _Float16* __restrict__ out) {
  __shared__ _Float16 Wl[16384];  // 32 KB
  int tid = threadIdx.x;
  int wid = tid >> 6;
  int lane = tid & 63;
  int r = lane & 15, kg = lane >> 4;
  int m0 = blockIdx.x * 128 + wid * 32;
  int row0 = min(m0 + r, NN - 1);
  int row1 = min(m0 + 16 + r, NN - 1);
  f32x4 acc0[8] = {}, acc1[8] = {};
  const _Float16* As[4] = {A0, A1, A2, A3};
#pragma unroll
  for (int s = 0; s < 4; ++s) {
    const float4* Wg = (const float4*)(Wt + (s << 14));  // 2048 granules of 16B
    __syncthreads();
#pragma unroll
    for (int u = 0; u < 8; ++u) {
      int g = tid + u * 256;
      int sg = g ^ ((g >> 4) & 7);
      *(float4*)((char*)Wl + g * 16) = Wg[sg];
    }
    __syncthreads();
    const _Float16* A = As[s];
    half8 a0[4], a1[4];
#pragma unroll
    for (int kc = 0; kc < 4; ++kc) {
      int kbase = kc * 32 + kg * 8;
      a0[kc] = *(const half8*)&A[(size_t)row0 * 128 + kbase];
      a1[kc] = *(const half8*)&A[(size_t)row1 * 128 + kbase];
    }
#pragma unroll
    for (int kc = 0; kc < 4; ++kc) {
      int kb2 = (kc * 32 + kg * 8) * 2;
#pragma unroll
      for (int nb = 0; nb < 8; ++nb) {
        int n = nb * 16 + r;
        int ba = ((n << 8) + kb2) ^ ((n & 7) << 4);
        half8 b = *(const half8*)((const char*)Wl + ba);
        acc0[nb] = __builtin_amdgcn_mfma_f32_16x16x32_f16(a0[kc], b, acc0[nb], 0, 0, 0);
        acc1[nb] = __builtin_amdgcn_mfma_f32_16x16x32_f16(a1[kc], b, acc1[nb], 0, 0, 0);
      }
    }
  }
  int ccol = lane & 15;
#pragma unroll
  for (int h = 0; h < 2; ++h) {
    int crow0 = m0 + h * 16 + kg * 4;
#pragma unroll
    for (int nb = 0; nb < 8; ++nb) {
      int col = nb * 16 + ccol;
      float bv = bias[col];
      const f32x4& av = h ? acc1[nb] : acc0[nb];
#pragma unroll
      for (int e = 0; e < 4; ++e) {
        float v = av[e] + bv;
        if (RELU) v = fmaxf(v, 0.f);
        int rr = crow0 + e;
        if (rr < NN) out[(size_t)rr * 128 + col] = (_Float16)v;
      }
    }
  }
}

// last layer fused with fc: out[n] = sum_s dot(A_s[n,:], uvec[s]) + cval
__global__ void k_tagfc(const _Float16* __restrict__ A0, const _Float16* __restrict__ A1,
                        const _Float16* __restrict__ A2, const _Float16* __restrict__ A3,
                        const float* __restrict__ uvec, const float* __restrict__ cval,
                        float* __restrict__ out) {
  int node = blockIdx.x;
  int t = threadIdx.x;  // 64, lane t covers feats [2t, 2t+1]
  const h2s* As[4] = {(const h2s*)A0, (const h2s*)A1, (const h2s*)A2, (const h2s*)A3};
  float s = 0.f;
#pragma unroll
  for (int q = 0; q < 4; ++q) {
    h2s v = As[q][(size_t)node * 64 + t];
    float2 u = ((const float2*)(uvec + (q << 7)))[t];
    s = fmaf((float)v.x, u.x, fmaf((float)v.y, u.y, s));
  }
  for (int o = 32; o; o >>= 1) s += __shfl_down(s, o);
  if (t == 0) out[node] = s + *cval;
}

// ---------------- conv0 fused (4 fp16 sources 16-wide -> 128, relu, fp16 out) ----------------
__global__ __launch_bounds__(256) void k_conv0_fused(
    const _Float16* __restrict__ A0, const _Float16* __restrict__ A1,
    const _Float16* __restrict__ A2, const _Float16* __restrict__ A3,
    const float* __restrict__ W /*[4][16][128]*/, const float* __restrict__ bias,
    _Float16* __restrict__ out) {
  __shared__ float Wl[4 * 16 * 128];
  for (int i = threadIdx.x * 4; i < 4 * 16 * 128; i += 1024)
    *(float4*)&Wl[i] = *(const float4*)&W[i];
  __syncthreads();
  int r0 = blockIdx.x * 32 + (threadIdx.x >> 5) * 4;
  int c0 = (threadIdx.x & 31) * 4;
  float acc[4][4] = {};
  const _Float16* As[4] = {A0, A1, A2, A3};
#pragma unroll
  for (int s = 0; s < 4; ++s) {
    const _Float16* A = As[s];
    const float* Ws = &Wl[s * 2048];
#pragma unroll
    for (int k = 0; k < 16; k += 4) {
      float4 w0 = *(const float4*)&Ws[(k + 0) * 128 + c0];
      float4 w1 = *(const float4*)&Ws[(k + 1) * 128 + c0];
      float4 w2 = *(const float4*)&Ws[(k + 2) * 128 + c0];
      float4 w3 = *(const float4*)&Ws[(k + 3) * 128 + c0];
#pragma unroll
      for (int i = 0; i < 4; ++i) {
        h4s a4 = *(const h4s*)&A[(r0 + i) * 16 + k];
        float ax = (float)a4.a, ay = (float)a4.b, az = (float)a4.c, aw = (float)a4.d;
        acc[i][0] = fmaf(ax, w0.x, fmaf(ay, w1.x, fmaf(az, w2.x, fmaf(aw, w3.x, acc[i][0]))));
        acc[i][1] = fmaf(ax, w0.y, fmaf(ay, w1.y, fmaf(az, w2.y, fmaf(aw, w3.y, acc[i][1]))));
        acc[i][2] = fmaf(ax, w0.z, fmaf(ay, w1.z, fmaf(az, w2.z, fmaf(aw, w3.z, acc[i][2]))));
        acc[i][3] = fmaf(ax, w0.w, fmaf(ay, w1.w, fmaf(az, w2.w, fmaf(aw, w3.w, acc[i][3]))));
      }
    }
  }
#pragma unroll
  for (int i = 0; i < 4; ++i) {
    h4s o;
    o.a = (_Float16)fmaxf(acc[i][0] + bias[c0 + 0], 0.f);
    o.b = (_Float16)fmaxf(acc[i][1] + bias[c0 + 1], 0.f);
    o.c = (_Float16)fmaxf(acc[i][2] + bias[c0 + 2], 0.f);
    o.d = (_Float16)fmaxf(acc[i][3] + bias[c0 + 3], 0.f);
    *(h4s*)&out[(size_t)(r0 + i) * 128 + c0] = o;
  }
}

// ---------------- feature embedding GEMM (fp32 in, fp16 out, 16 cols) ----------------
template <int IN, bool ACCUM, bool BIAS>
__global__ void k_mm16h(const float* __restrict__ A, const float* __restrict__ W,
                        const float* __restrict__ bias, _Float16* __restrict__ C) {
  __shared__ float Wl[IN * 16];
  for (int i = threadIdx.x; i < IN * 16; i += 256) Wl[i] = W[i];
  __syncthreads();
  int r = blockIdx.x * 16 + (threadIdx.x >> 4);
  int c = threadIdx.x & 15;
  float acc = 0.f;
  for (int k = 0; k < IN; ++k) acc += A[r * IN + k] * Wl[k * 16 + c];
  int idx = r * 16 + c;
  if (BIAS) acc += bias[c];
  if (ACCUM) acc += (float)C[idx];
  C[idx] = (_Float16)acc;
}

extern "C" void kernel_launch(void* const* d_in, const int* in_sizes, int n_in,
                              void* d_out, int out_size, void* d_ws, size_t ws_size,
                              hipStream_t stream) {
  const float* x = (const float*)d_in[0];
  const int* ei = (const int*)d_in[1];
  const float* fe_ws = (const float*)d_in[2];
  const float* fe_b = (const float*)d_in[3];
  const float* c0_ws = (const float*)d_in[4];
  const float* c0_b = (const float*)d_in[5];
  const float* cw = (const float*)d_in[6];
  const float* cb = (const float*)d_in[7];
  const float* fcw = (const float*)d_in[8];
  const float* fcb = (const float*)d_in[9];
  float* out = (float*)d_out;

  const int* row = ei;
  const int* colv = ei + NE;

  char* wp = (char*)d_ws;
  auto alloc = [&](size_t bytes) {
    char* p = wp;
    wp += (bytes + 511) & ~(size_t)511;
    return p;
  };
  int* degi = (int*)alloc(NN * 4);
  int* off = (int*)alloc((NN + 1) * 4);
  int* bsum = (int*)alloc(SCAN_B * 4);
  int* boff = (int*)alloc(SCAN_B * 4);
  int* bcur = (int*)alloc((size_t)NB * 8 * 16 * 4);
  float* dis = (float*)alloc(NN * 4);
  int* src = (int*)alloc((size_t)NE * 4);
  unsigned* pk2 = (unsigned*)alloc((size_t)NB * 8 * SUBCAP * 4);
  _Float16* wh = (_Float16*)alloc((size_t)NE * 2);
  _Float16* wsT = (_Float16*)alloc((size_t)12 * 16384 * 2);
  float* uvec = (float*)alloc(512 * 4);
  float* cval = (float*)alloc(4);
  _Float16* y1h = (_Float16*)alloc((size_t)NN * 16 * 2);
  _Float16* h16 = (_Float16*)alloc((size_t)NN * 16 * 2);
  _Float16* p16b = (_Float16*)alloc((size_t)NN * 16 * 2);
  _Float16* p16c = (_Float16*)alloc((size_t)NN * 16 * 2);
  _Float16* p16d = (_Float16*)alloc((size_t)NN * 16 * 2);
  _Float16* H0 = (_Float16*)alloc((size_t)NN * 128 * 2);
  _Float16* H1 = (_Float16*)alloc((size_t)NN * 128 * 2);
  _Float16* T1 = (_Float16*)alloc((size_t)NN * 128 * 2);
  _Float16* T2 = (_Float16*)alloc((size_t)NN * 128 * 2);
  _Float16* T3 = (_Float16*)alloc((size_t)NN * 128 * 2);

  // ---- graph prep ----
  hipMemsetAsync(degi, 0, NN * 4, stream);
  hipMemsetAsync(bcur, 0, (size_t)NB * 8 * 16 * 4, stream);
  k_bscatter<<<(NE + 255) / 256, 256, 0, stream>>>(row, colv, degi, bcur, pk2);
  k_dis<<<(NN + 255) / 256, 256, 0, stream>>>(degi, dis);
  k_scan1<<<SCAN_B, 256, 0, stream>>>(degi, bsum);
  k_scan2<<<1, 128, 0, stream>>>(bsum, boff, off);
  k_scan3<<<SCAN_B, 256, 0, stream>>>(degi, boff, off);
  k_bsort<<<NB, 256, 0, stream>>>(pk2, bcur, off, dis, src, wh);
  k_wprep<<<768, 256, 0, stream>>>(cw, wsT);
  k_uprep<<<3, 256, 0, stream>>>(cw, cb, fcw, fcb, uvec, cval);

  // ---- featureEmbedding: h16 = x@W0 + A(x@W1) + b  (prop commutes with W) ----
  k_mm16h<17, false, false><<<NN / 16, 256, 0, stream>>>(x, fe_ws + 17 * 16, nullptr, y1h);
  k_prop16h<<<NN / 8, 64, 0, stream>>>((const h2s*)y1h, off, src, wh, (h2s*)h16);
  k_mm16h<17, true, true><<<NN / 16, 256, 0, stream>>>(x, fe_ws, fe_b, h16);

  // ---- conv0 (16 -> 128, K=3, relu) -> H0 fp16 ----
  k_prop16h<<<NN / 8, 64, 0, stream>>>((const h2s*)h16, off, src, wh, (h2s*)p16b);
  k_prop16h<<<NN / 8, 64, 0, stream>>>((const h2s*)p16b, off, src, wh, (h2s*)p16c);
  k_prop16h<<<NN / 8, 64, 0, stream>>>((const h2s*)p16c, off, src, wh, (h2s*)p16d);
  k_conv0_fused<<<NN / 32, 256, 0, stream>>>(h16, p16b, p16c, p16d, c0_ws, c0_b, H0);

  // ---- conv1..2 (128 -> 128, K=3): 3 props + fused MFMA GEMM each ----
  _Float16* hin = H0;
  _Float16* hout = H1;
  int mgrid = (NN + 127) / 128;
  int pgrid = NN / 2;  // 2 waves per 128-thr block, one node per wave
  for (int l = 0; l < 2; ++l) {
    k_prop128h<<<pgrid, 128, 0, stream>>>((const h2s*)hin, off, src, wh, (h2s*)T1);
    k_prop128h<<<pgrid, 128, 0, stream>>>((const h2s*)T1, off, src, wh, (h2s*)T2);
    k_prop128h<<<pgrid, 128, 0, stream>>>((const h2s*)T2, off, src, wh, (h2s*)T3);
    const _Float16* Wl = wsT + (size_t)l * 4 * 16384;
    const float* bl = cb + l * 128;
    k_tag4_mfma<true><<<mgrid, 256, 0, stream>>>(hin, T1, T2, T3, Wl, bl, hout);
    _Float16* t = hin; hin = hout; hout = t;
  }

  // ---- conv3 fused with fc: 3 props + dot against folded weights ----
  k_prop128h<<<pgrid, 128, 0, stream>>>((const h2s*)hin, off, src, wh, (h2s*)T1);
  k_prop128h<<<pgrid, 128, 0, stream>>>((const h2s*)T1, off, src, wh, (h2s*)T2);
  k_prop128h<<<pgrid, 128, 0, stream>>>((const h2s*)T2, off, src, wh, (h2s*)T3);
  k_tagfc<<<NN, 64, 0, stream>>>(hin, T1, T2, T3, uvec, cval, out);
}

// Round 12
// 945.285 us; speedup vs baseline: 1.1283x; 1.0090x over previous
//
#include <hip/hip_runtime.h>

#define NN 100000
#define NE 1600000
#define SCAN_B 98   // 98*1024 >= NN
#define NB 782      // buckets of 128 nodes: 782*128 >= NN
#define SUBCAP 512  // per (bucket,xcd) capacity; mean 256, 512 ~ +16 sigma
#define MAXB 4096   // 8*SUBCAP — guaranteed LDS bound

typedef _Float16 half8 __attribute__((ext_vector_type(8)));
typedef float f32x4 __attribute__((ext_vector_type(4)));
struct h2s { _Float16 x, y; };
struct h4s { _Float16 a, b, c, d; };

// ---------------- graph prep ----------------
__global__ void k_deg(const int* __restrict__ col, int* __restrict__ degi) {
  int e = blockIdx.x * blockDim.x + threadIdx.x;
  if (e < NE) atomicAdd(&degi[col[e]], 1);
}

__global__ void k_dis(const int* __restrict__ degi, float* __restrict__ dis) {
  int i = blockIdx.x * blockDim.x + threadIdx.x;
  if (i < NN) {
    int d = degi[i];
    dis[i] = d > 0 ? rsqrtf((float)d) : 0.0f;
  }
}

__global__ void k_scan1(const int* __restrict__ degi, int* __restrict__ bsum) {
  __shared__ int red[256];
  int t = threadIdx.x;
  int base = blockIdx.x * 1024 + t * 4;
  int s = 0;
#pragma unroll
  for (int u = 0; u < 4; ++u) {
    int i = base + u;
    if (i < NN) s += degi[i];
  }
  red[t] = s;
  __syncthreads();
  for (int o = 128; o; o >>= 1) {
    if (t < o) red[t] += red[t + o];
    __syncthreads();
  }
  if (t == 0) bsum[blockIdx.x] = red[0];
}

__global__ void k_scan2(const int* __restrict__ bsum, int* __restrict__ boff,
                        int* __restrict__ off) {
  __shared__ int sh[128];
  int t = threadIdx.x;  // 128
  int v = (t < SCAN_B) ? bsum[t] : 0;
  sh[t] = v;
  __syncthreads();
  for (int o = 1; o < 128; o <<= 1) {
    int u = (t >= o) ? sh[t - o] : 0;
    __syncthreads();
    sh[t] += u;
    __syncthreads();
  }
  if (t < SCAN_B) boff[t] = sh[t] - v;
  if (t == 127) off[NN] = sh[127];
}

__global__ void k_scan3(const int* __restrict__ degi, const int* __restrict__ boff,
                        int* __restrict__ off) {
  __shared__ int red[256];
  int t = threadIdx.x;
  int base = blockIdx.x * 1024 + t * 4;
  int d[4];
  int s = 0;
#pragma unroll
  for (int u = 0; u < 4; ++u) {
    int i = base + u;
    d[u] = (i < NN) ? degi[i] : 0;
    s += d[u];
  }
  red[t] = s;
  __syncthreads();
  for (int o = 1; o < 256; o <<= 1) {
    int u2 = (t >= o) ? red[t - o] : 0;
    __syncthreads();
    red[t] += u2;
    __syncthreads();
  }
  int pre = red[t] - s + boff[blockIdx.x];
#pragma unroll
  for (int u = 0; u < 4; ++u) {
    int i = base + u;
    if (i < NN) {
      off[i] = pre;
      pre += d[u];
    }
  }
}

// Phase B: scatter packed {row, col&127} into per-(bucket,XCD) sub-buckets.
// x = blockIdx & 7 tracks round-robin block->XCD so each cell's write front is
// exclusive to one XCD L2 -> full lines, single writeback. (Round-9 form.)
__global__ void k_bscatter(const int* __restrict__ row, const int* __restrict__ col,
                           int* __restrict__ bcur, unsigned* __restrict__ pk2) {
  int e = blockIdx.x * blockDim.x + threadIdx.x;
  int x = blockIdx.x & 7;
  if (e < NE) {
    int c = col[e];
    int cell = ((c >> 7) << 3) | x;
    int slot = atomicAdd(&bcur[cell * 16], 1);
    slot = min(slot, SUBCAP - 1);  // statistically unreachable (16 sigma)
    pk2[(size_t)cell * SUBCAP + slot] = (unsigned)row[e] | ((unsigned)(c & 127) << 17);
  }
}

// Phase C: per-bucket LDS counting sort over 8 sub-segments -> sequential src+wh
__global__ __launch_bounds__(256) void k_bsort(const unsigned* __restrict__ pk2,
                                               const int* __restrict__ bcur,
                                               const int* __restrict__ off,
                                               const float* __restrict__ dis,
                                               int* __restrict__ src,
                                               _Float16* __restrict__ wh) {
  __shared__ unsigned epk[MAXB];
  __shared__ int cnt[128];
  __shared__ int sc[128];
  __shared__ int cur[128];
  __shared__ float sdis[128];
  __shared__ int soff[9];
  int b = blockIdx.x;
  int n0 = b << 7;
  int gb = off[n0];
  int t = threadIdx.x;
  if (t == 0) {
    int acc = 0;
#pragma unroll
    for (int x = 0; x < 8; ++x) {
      soff[x] = acc;
      acc += min(bcur[((b << 3) | x) * 16], SUBCAP);
    }
    soff[8] = acc;
  }
  if (t < 128) {
    cnt[t] = 0;
    sdis[t] = (n0 + t < NN) ? dis[n0 + t] : 0.f;
  }
  __syncthreads();
  int m = soff[8];
#pragma unroll
  for (int x = 0; x < 8; ++x) {
    int c0 = soff[x], c1 = soff[x + 1];
    const unsigned* seg = &pk2[(size_t)((b << 3) | x) * SUBCAP];
    for (int i = c0 + t; i < c1; i += 256) epk[i] = seg[i - c0];
  }
  __syncthreads();
  for (int i = t; i < m; i += 256) atomicAdd(&cnt[epk[i] >> 17], 1);
  __syncthreads();
  if (t < 128) sc[t] = cnt[t];
  __syncthreads();
  for (int o = 1; o < 128; o <<= 1) {
    int u = (t < 128 && t >= o) ? sc[t - o] : 0;
    __syncthreads();
    if (t < 128) sc[t] += u;
    __syncthreads();
  }
  if (t < 128) cur[t] = sc[t] - cnt[t];  // exclusive
  __syncthreads();
  for (int i = t; i < m; i += 256) {
    unsigned p = epk[i];
    int c = (int)(p >> 17);
    int r = (int)(p & 0x1FFFFu);
    int pos = gb + atomicAdd(&cur[c], 1);
    src[pos] = r;
    wh[pos] = (_Float16)(dis[r] * sdis[c]);
  }
}

// convert+transpose conv weights: cw [12][128k][128n] f32 -> wt [12][128n][128k] f16
__global__ void k_wprep(const float* __restrict__ cw, _Float16* __restrict__ wt) {
  int i = blockIdx.x * 256 + threadIdx.x;
  if (i < 12 * 16384) {
    int mat = i >> 14;
    int rem = i & 16383;
    int k = rem >> 7;
    int n = rem & 127;
    wt[(mat << 14) | (n << 7) | k] = (_Float16)cw[i];
  }
}

// last layer fold: uvec[s][k] = sum_n W3_s[k][n]*fcw[n]; cval = cb3.fcw + fcb
__global__ void k_uprep(const float* __restrict__ cw, const float* __restrict__ cb,
                        const float* __restrict__ fcw, const float* __restrict__ fcb,
                        float* __restrict__ uvec, float* __restrict__ cval) {
  int i = blockIdx.x * 256 + threadIdx.x;
  if (i < 512) {
    int s = i >> 7, k = i & 127;
    const float* W = cw + (size_t)(8 + s) * 16384 + k * 128;
    float acc = 0.f;
    for (int n = 0; n < 128; ++n) acc += W[n] * fcw[n];
    uvec[i] = acc;
  }
  if (i == 512) {
    float acc = 0.f;
    for (int n = 0; n < 128; ++n) acc += cb[2 * 128 + n] * fcw[n];
    *cval = acc + fcb[0];
  }
}

// ---------------- propagation ----------------
// fp16 16-wide: 8 lanes per node, 8 nodes per 64-thread block (3.2MB, L2-friendly)
__global__ void k_prop16h(const h2s* __restrict__ h, const int* __restrict__ off,
                          const int* __restrict__ src, const _Float16* __restrict__ wh,
                          h2s* __restrict__ out) {
  int t = threadIdx.x;  // 64
  int node = blockIdx.x * 8 + (t >> 3);
  int f = t & 7;
  int b = off[node], e = off[node + 1];
  float ax = 0.f, ay = 0.f;
  int j = b;
  for (; j + 2 <= e; j += 2) {
    int s0 = src[j], s1 = src[j + 1];
    float w0 = (float)wh[j], w1 = (float)wh[j + 1];
    h2s v0 = h[s0 * 8 + f];
    h2s v1 = h[s1 * 8 + f];
    ax = fmaf((float)v0.x, w0, fmaf((float)v1.x, w1, ax));
    ay = fmaf((float)v0.y, w0, fmaf((float)v1.y, w1, ay));
  }
  if (j < e) {
    int s = src[j];
    float w = (float)wh[j];
    h2s v = h[s * 8 + f];
    ax = fmaf((float)v.x, w, ax);
    ay = fmaf((float)v.y, w, ay);
  }
  h2s o;
  o.x = (_Float16)ax;
  o.y = (_Float16)ay;
  unsigned bits;
  __builtin_memcpy(&bits, &o, 4);
  __builtin_nontemporal_store(bits, (unsigned*)&out[node * 8 + f]);
}

// fp16 128-wide contiguous: one node per WAVE (node wave-uniform so src/wh
// metadata stays on the scalar-load path), 2 waves per 128-thr block.
__global__ __launch_bounds__(128) void k_prop128h(const h2s* __restrict__ h,
                                                  const int* __restrict__ off,
                                                  const int* __restrict__ src,
                                                  const _Float16* __restrict__ wh,
                                                  h2s* __restrict__ out) {
  int wid = __builtin_amdgcn_readfirstlane(threadIdx.x >> 6);
  int node = blockIdx.x * 2 + wid;
  int t = threadIdx.x & 63;
  int b = off[node], e = off[node + 1];
  float ax = 0.f, ay = 0.f;
  int j = b;
  for (; j + 8 <= e; j += 8) {
    h2s v[8];
    float w[8];
#pragma unroll
    for (int u = 0; u < 8; ++u) {
      v[u] = h[src[j + u] * 64 + t];
      w[u] = (float)wh[j + u];
    }
#pragma unroll
    for (int u = 0; u < 8; ++u) {
      ax = fmaf((float)v[u].x, w[u], ax);
      ay = fmaf((float)v[u].y, w[u], ay);
    }
  }
  for (; j < e; ++j) {
    int s = src[j];
    float w = (float)wh[j];
    h2s v = h[s * 64 + t];
    ax = fmaf((float)v.x, w, ax);
    ay = fmaf((float)v.y, w, ay);
  }
  h2s o;
  o.x = (_Float16)ax;
  o.y = (_Float16)ay;
  unsigned bits;
  __builtin_memcpy(&bits, &o, 4);
  __builtin_nontemporal_store(bits, (unsigned*)&out[node * 64 + t]);
}

// ---------------- fused TAG layer GEMM (128->128, 4 sources, MFMA f16) ----------------
template <bool RELU>
__global__ __launch_bounds__(256) void k_tag4_mfma(
    const _Float16* __restrict__ A0, const _Float16* __restrict__ A1,
    const _Float16* __restrict__ A2, const _Float16* __restrict__ A3,
    const _Float16* __restrict__ Wt, const float* __restrict__ bias,
    _Float16* __restrict__ out) {
  __shared__ _Float16 Wl[16384];  // 32 KB
  int tid = threadIdx.x;
  int wid = tid >> 6;
  int lane = tid & 63;
  int r = lane & 15, kg = lane >> 4;
  int m0 = blockIdx.x * 128 + wid * 32;
  int row0 = min(m0 + r, NN - 1);
  int row1 = min(m0 + 16 + r, NN - 1);
  f32x4 acc0[8] = {}, acc1[8] = {};
  const _Float16* As[4] = {A0, A1, A2, A3};
#pragma unroll
  for (int s = 0; s < 4; ++s) {
    const float4* Wg = (const float4*)(Wt + (s << 14));  // 2048 granules of 16B
    __syncthreads();
#pragma unroll
    for (int u = 0; u < 8; ++u) {
      int g = tid + u * 256;
      int sg = g ^ ((g >> 4) & 7);
      *(float4*)((char*)Wl + g * 16) = Wg[sg];
    }
    __syncthreads();
    const _Float16* A = As[s];
    half8 a0[4], a1[4];
#pragma unroll
    for (int kc = 0; kc < 4; ++kc) {
      int kbase = kc * 32 + kg * 8;
      a0[kc] = *(const half8*)&A[(size_t)row0 * 128 + kbase];
      a1[kc] = *(const half8*)&A[(size_t)row1 * 128 + kbase];
    }
#pragma unroll
    for (int kc = 0; kc < 4; ++kc) {
      int kb2 = (kc * 32 + kg * 8) * 2;
#pragma unroll
      for (int nb = 0; nb < 8; ++nb) {
        int n = nb * 16 + r;
        int ba = ((n << 8) + kb2) ^ ((n & 7) << 4);
        half8 b = *(const half8*)((const char*)Wl + ba);
        acc0[nb] = __builtin_amdgcn_mfma_f32_16x16x32_f16(a0[kc], b, acc0[nb], 0, 0, 0);
        acc1[nb] = __builtin_amdgcn_mfma_f32_16x16x32_f16(a1[kc], b, acc1[nb], 0, 0, 0);
      }
    }
  }
  int ccol = lane & 15;
#pragma unroll
  for (int h = 0; h < 2; ++h) {
    int crow0 = m0 + h * 16 + kg * 4;
#pragma unroll
    for (int nb = 0; nb < 8; ++nb) {
      int col = nb * 16 + ccol;
      float bv = bias[col];
      const f32x4& av = h ? acc1[nb] : acc0[nb];
#pragma unroll
      for (int e = 0; e < 4; ++e) {
        float v = av[e] + bv;
        if (RELU) v = fmaxf(v, 0.f);
        int rr = crow0 + e;
        if (rr < NN) out[(size_t)rr * 128 + col] = (_Float16)v;
      }
    }
  }
}

// last layer fused with fc: out[n] = sum_s dot(A_s[n,:], uvec[s]) + cval
__global__ void k_tagfc(const _Float16* __restrict__ A0, const _Float16* __restrict__ A1,
                        const _Float16* __restrict__ A2, const _Float16* __restrict__ A3,
                        const float* __restrict__ uvec, const float* __restrict__ cval,
                        float* __restrict__ out) {
  int node = blockIdx.x;
  int t = threadIdx.x;  // 64, lane t covers feats [2t, 2t+1]
  const h2s* As[4] = {(const h2s*)A0, (const h2s*)A1, (const h2s*)A2, (const h2s*)A3};
  float s = 0.f;
#pragma unroll
  for (int q = 0; q < 4; ++q) {
    h2s v = As[q][(size_t)node * 64 + t];
    float2 u = ((const float2*)(uvec + (q << 7)))[t];
    s = fmaf((float)v.x, u.x, fmaf((float)v.y, u.y, s));
  }
  for (int o = 32; o; o >>= 1) s += __shfl_down(s, o);
  if (t == 0) out[node] = s + *cval;
}

// ---------------- conv0 fused (4 fp16 sources 16-wide -> 128, relu, fp16 out) ----------------
__global__ __launch_bounds__(256) void k_conv0_fused(
    const _Float16* __restrict__ A0, const _Float16* __restrict__ A1,
    const _Float16* __restrict__ A2, const _Float16* __restrict__ A3,
    const float* __restrict__ W /*[4][16][128]*/, const float* __restrict__ bias,
    _Float16* __restrict__ out) {
  __shared__ float Wl[4 * 16 * 128];
  for (int i = threadIdx.x * 4; i < 4 * 16 * 128; i += 1024)
    *(float4*)&Wl[i] = *(const float4*)&W[i];
  __syncthreads();
  int r0 = blockIdx.x * 32 + (threadIdx.x >> 5) * 4;
  int c0 = (threadIdx.x & 31) * 4;
  float acc[4][4] = {};
  const _Float16* As[4] = {A0, A1, A2, A3};
#pragma unroll
  for (int s = 0; s < 4; ++s) {
    const _Float16* A = As[s];
    const float* Ws = &Wl[s * 2048];
#pragma unroll
    for (int k = 0; k < 16; k += 4) {
      float4 w0 = *(const float4*)&Ws[(k + 0) * 128 + c0];
      float4 w1 = *(const float4*)&Ws[(k + 1) * 128 + c0];
      float4 w2 = *(const float4*)&Ws[(k + 2) * 128 + c0];
      float4 w3 = *(const float4*)&Ws[(k + 3) * 128 + c0];
#pragma unroll
      for (int i = 0; i < 4; ++i) {
        h4s a4 = *(const h4s*)&A[(r0 + i) * 16 + k];
        float ax = (float)a4.a, ay = (float)a4.b, az = (float)a4.c, aw = (float)a4.d;
        acc[i][0] = fmaf(ax, w0.x, fmaf(ay, w1.x, fmaf(az, w2.x, fmaf(aw, w3.x, acc[i][0]))));
        acc[i][1] = fmaf(ax, w0.y, fmaf(ay, w1.y, fmaf(az, w2.y, fmaf(aw, w3.y, acc[i][1]))));
        acc[i][2] = fmaf(ax, w0.z, fmaf(ay, w1.z, fmaf(az, w2.z, fmaf(aw, w3.z, acc[i][2]))));
        acc[i][3] = fmaf(ax, w0.w, fmaf(ay, w1.w, fmaf(az, w2.w, fmaf(aw, w3.w, acc[i][3]))));
      }
    }
  }
#pragma unroll
  for (int i = 0; i < 4; ++i) {
    h4s o;
    o.a = (_Float16)fmaxf(acc[i][0] + bias[c0 + 0], 0.f);
    o.b = (_Float16)fmaxf(acc[i][1] + bias[c0 + 1], 0.f);
    o.c = (_Float16)fmaxf(acc[i][2] + bias[c0 + 2], 0.f);
    o.d = (_Float16)fmaxf(acc[i][3] + bias[c0 + 3], 0.f);
    *(h4s*)&out[(size_t)(r0 + i) * 128 + c0] = o;
  }
}

// ---------------- feature embedding GEMM (fp32 in, fp16 out, 16 cols) ----------------
template <int IN, bool ACCUM, bool BIAS>
__global__ void k_mm16h(const float* __restrict__ A, const float* __restrict__ W,
                        const float* __restrict__ bias, _Float16* __restrict__ C) {
  __shared__ float Wl[IN * 16];
  for (int i = threadIdx.x; i < IN * 16; i += 256) Wl[i] = W[i];
  __syncthreads();
  int r = blockIdx.x * 16 + (threadIdx.x >> 4);
  int c = threadIdx.x & 15;
  float acc = 0.f;
  for (int k = 0; k < IN; ++k) acc += A[r * IN + k] * Wl[k * 16 + c];
  int idx = r * 16 + c;
  if (BIAS) acc += bias[c];
  if (ACCUM) acc += (float)C[idx];
  C[idx] = (_Float16)acc;
}

extern "C" void kernel_launch(void* const* d_in, const int* in_sizes, int n_in,
                              void* d_out, int out_size, void* d_ws, size_t ws_size,
                              hipStream_t stream) {
  const float* x = (const float*)d_in[0];
  const int* ei = (const int*)d_in[1];
  const float* fe_ws = (const float*)d_in[2];
  const float* fe_b = (const float*)d_in[3];
  const float* c0_ws = (const float*)d_in[4];
  const float* c0_b = (const float*)d_in[5];
  const float* cw = (const float*)d_in[6];
  const float* cb = (const float*)d_in[7];
  const float* fcw = (const float*)d_in[8];
  const float* fcb = (const float*)d_in[9];
  float* out = (float*)d_out;

  const int* row = ei;
  const int* colv = ei + NE;

  char* wp = (char*)d_ws;
  auto alloc = [&](size_t bytes) {
    char* p = wp;
    wp += (bytes + 511) & ~(size_t)511;
    return p;
  };
  int* degi = (int*)alloc(NN * 4);
  int* off = (int*)alloc((NN + 1) * 4);
  int* bsum = (int*)alloc(SCAN_B * 4);
  int* boff = (int*)alloc(SCAN_B * 4);
  int* bcur = (int*)alloc((size_t)NB * 8 * 16 * 4);
  float* dis = (float*)alloc(NN * 4);
  int* src = (int*)alloc((size_t)NE * 4);
  unsigned* pk2 = (unsigned*)alloc((size_t)NB * 8 * SUBCAP * 4);
  _Float16* wh = (_Float16*)alloc((size_t)NE * 2);
  _Float16* wsT = (_Float16*)alloc((size_t)12 * 16384 * 2);
  float* uvec = (float*)alloc(512 * 4);
  float* cval = (float*)alloc(4);
  _Float16* y1h = (_Float16*)alloc((size_t)NN * 16 * 2);
  _Float16* h16 = (_Float16*)alloc((size_t)NN * 16 * 2);
  _Float16* p16b = (_Float16*)alloc((size_t)NN * 16 * 2);
  _Float16* p16c = (_Float16*)alloc((size_t)NN * 16 * 2);
  _Float16* p16d = (_Float16*)alloc((size_t)NN * 16 * 2);
  _Float16* H0 = (_Float16*)alloc((size_t)NN * 128 * 2);
  _Float16* H1 = (_Float16*)alloc((size_t)NN * 128 * 2);
  _Float16* T1 = (_Float16*)alloc((size_t)NN * 128 * 2);
  _Float16* T2 = (_Float16*)alloc((size_t)NN * 128 * 2);
  _Float16* T3 = (_Float16*)alloc((size_t)NN * 128 * 2);

  // ---- graph prep ----
  hipMemsetAsync(degi, 0, NN * 4, stream);
  hipMemsetAsync(bcur, 0, (size_t)NB * 8 * 16 * 4, stream);
  k_deg<<<(NE + 255) / 256, 256, 0, stream>>>(colv, degi);
  k_dis<<<(NN + 255) / 256, 256, 0, stream>>>(degi, dis);
  k_scan1<<<SCAN_B, 256, 0, stream>>>(degi, bsum);
  k_scan2<<<1, 128, 0, stream>>>(bsum, boff, off);
  k_scan3<<<SCAN_B, 256, 0, stream>>>(degi, boff, off);
  k_bscatter<<<(NE + 255) / 256, 256, 0, stream>>>(row, colv, bcur, pk2);
  k_bsort<<<NB, 256, 0, stream>>>(pk2, bcur, off, dis, src, wh);
  k_wprep<<<768, 256, 0, stream>>>(cw, wsT);
  k_uprep<<<3, 256, 0, stream>>>(cw, cb, fcw, fcb, uvec, cval);

  // ---- featureEmbedding: h16 = x@W0 + A(x@W1) + b  (prop commutes with W) ----
  k_mm16h<17, false, false><<<NN / 16, 256, 0, stream>>>(x, fe_ws + 17 * 16, nullptr, y1h);
  k_prop16h<<<NN / 8, 64, 0, stream>>>((const h2s*)y1h, off, src, wh, (h2s*)h16);
  k_mm16h<17, true, true><<<NN / 16, 256, 0, stream>>>(x, fe_ws, fe_b, h16);

  // ---- conv0 (16 -> 128, K=3, relu) -> H0 fp16 ----
  k_prop16h<<<NN / 8, 64, 0, stream>>>((const h2s*)h16, off, src, wh, (h2s*)p16b);
  k_prop16h<<<NN / 8, 64, 0, stream>>>((const h2s*)p16b, off, src, wh, (h2s*)p16c);
  k_prop16h<<<NN / 8, 64, 0, stream>>>((const h2s*)p16c, off, src, wh, (h2s*)p16d);
  k_conv0_fused<<<NN / 32, 256, 0, stream>>>(h16, p16b, p16c, p16d, c0_ws, c0_b, H0);

  // ---- conv1..2 (128 -> 128, K=3): 3 props + fused MFMA GEMM each ----
  _Float16* hin = H0;
  _Float16* hout = H1;
  int mgrid = (NN + 127) / 128;
  int pgrid = NN / 2;  // 2 waves per 128-thr block, one node per wave
  for (int l = 0; l < 2; ++l) {
    k_prop128h<<<pgrid, 128, 0, stream>>>((const h2s*)hin, off, src, wh, (h2s*)T1);
    k_prop128h<<<pgrid, 128, 0, stream>>>((const h2s*)T1, off, src, wh, (h2s*)T2);
    k_prop128h<<<pgrid, 128, 0, stream>>>((const h2s*)T2, off, src, wh, (h2s*)T3);
    const _Float16* Wl = wsT + (size_t)l * 4 * 16384;
    const float* bl = cb + l * 128;
    k_tag4_mfma<true><<<mgrid, 256, 0, stream>>>(hin, T1, T2, T3, Wl, bl, hout);
    _Float16* t = hin; hin = hout; hout = t;
  }

  // ---- conv3 fused with fc: 3 props + dot against folded weights ----
  k_prop128h<<<pgrid, 128, 0, stream>>>((const h2s*)hin, off, src, wh, (h2s*)T1);
  k_prop128h<<<pgrid, 128, 0, stream>>>((const h2s*)T1, off, src, wh, (h2s*)T2);
  k_prop128h<<<pgrid, 128, 0, stream>>>((const h2s*)T2, off, src, wh, (h2s*)T3);
  k_tagfc<<<NN, 64, 0, stream>>>(hin, T1, T2, T3, uvec, cval, out);
}

// Round 13
// 819.083 us; speedup vs baseline: 1.3022x; 1.1541x over previous
//
#include <hip/hip_runtime.h>

#define NN 100000
#define NE 1600000
#define SCAN_B 98   // 98*1024 >= NN
#define NB 782      // buckets of 128 nodes: 782*128 >= NN
#define SUBCAP 512  // per (bucket,xcd) capacity; mean 256, 512 ~ +16 sigma
#define MAXB 4096   // 8*SUBCAP — guaranteed LDS bound

typedef _Float16 half8 __attribute__((ext_vector_type(8)));
typedef float f32x4 __attribute__((ext_vector_type(4)));
struct h2s { _Float16 x, y; };
struct h4s { _Float16 a, b, c, d; };

// ---------------- graph prep ----------------
__global__ void k_deg(const int* __restrict__ col, int* __restrict__ degi) {
  int e = blockIdx.x * blockDim.x + threadIdx.x;
  if (e < NE) atomicAdd(&degi[col[e]], 1);
}

__global__ void k_dis(const int* __restrict__ degi, float* __restrict__ dis) {
  int i = blockIdx.x * blockDim.x + threadIdx.x;
  if (i < NN) {
    int d = degi[i];
    dis[i] = d > 0 ? rsqrtf((float)d) : 0.0f;
  }
}

__global__ void k_scan1(const int* __restrict__ degi, int* __restrict__ bsum) {
  __shared__ int red[256];
  int t = threadIdx.x;
  int base = blockIdx.x * 1024 + t * 4;
  int s = 0;
#pragma unroll
  for (int u = 0; u < 4; ++u) {
    int i = base + u;
    if (i < NN) s += degi[i];
  }
  red[t] = s;
  __syncthreads();
  for (int o = 128; o; o >>= 1) {
    if (t < o) red[t] += red[t + o];
    __syncthreads();
  }
  if (t == 0) bsum[blockIdx.x] = red[0];
}

__global__ void k_scan2(const int* __restrict__ bsum, int* __restrict__ boff,
                        int* __restrict__ off) {
  __shared__ int sh[128];
  int t = threadIdx.x;  // 128
  int v = (t < SCAN_B) ? bsum[t] : 0;
  sh[t] = v;
  __syncthreads();
  for (int o = 1; o < 128; o <<= 1) {
    int u = (t >= o) ? sh[t - o] : 0;
    __syncthreads();
    sh[t] += u;
    __syncthreads();
  }
  if (t < SCAN_B) boff[t] = sh[t] - v;
  if (t == 127) off[NN] = sh[127];
}

__global__ void k_scan3(const int* __restrict__ degi, const int* __restrict__ boff,
                        int* __restrict__ off) {
  __shared__ int red[256];
  int t = threadIdx.x;
  int base = blockIdx.x * 1024 + t * 4;
  int d[4];
  int s = 0;
#pragma unroll
  for (int u = 0; u < 4; ++u) {
    int i = base + u;
    d[u] = (i < NN) ? degi[i] : 0;
    s += d[u];
  }
  red[t] = s;
  __syncthreads();
  for (int o = 1; o < 256; o <<= 1) {
    int u2 = (t >= o) ? red[t - o] : 0;
    __syncthreads();
    red[t] += u2;
    __syncthreads();
  }
  int pre = red[t] - s + boff[blockIdx.x];
#pragma unroll
  for (int u = 0; u < 4; ++u) {
    int i = base + u;
    if (i < NN) {
      off[i] = pre;
      pre += d[u];
    }
  }
}

// Phase B: scatter packed {row, col&127} into per-(bucket,XCD) sub-buckets.
__global__ void k_bscatter(const int* __restrict__ row, const int* __restrict__ col,
                           int* __restrict__ bcur, unsigned* __restrict__ pk2) {
  int e = blockIdx.x * blockDim.x + threadIdx.x;
  int x = blockIdx.x & 7;
  if (e < NE) {
    int c = col[e];
    int cell = ((c >> 7) << 3) | x;
    int slot = atomicAdd(&bcur[cell * 16], 1);
    slot = min(slot, SUBCAP - 1);  // statistically unreachable (16 sigma)
    pk2[(size_t)cell * SUBCAP + slot] = (unsigned)row[e] | ((unsigned)(c & 127) << 17);
  }
}

// Phase C: per-bucket LDS counting sort over 8 sub-segments -> sequential src+wh
__global__ __launch_bounds__(256) void k_bsort(const unsigned* __restrict__ pk2,
                                               const int* __restrict__ bcur,
                                               const int* __restrict__ off,
                                               const float* __restrict__ dis,
                                               int* __restrict__ src,
                                               _Float16* __restrict__ wh) {
  __shared__ unsigned epk[MAXB];
  __shared__ int cnt[128];
  __shared__ int sc[128];
  __shared__ int cur[128];
  __shared__ float sdis[128];
  __shared__ int soff[9];
  int b = blockIdx.x;
  int n0 = b << 7;
  int gb = off[n0];
  int t = threadIdx.x;
  if (t == 0) {
    int acc = 0;
#pragma unroll
    for (int x = 0; x < 8; ++x) {
      soff[x] = acc;
      acc += min(bcur[((b << 3) | x) * 16], SUBCAP);
    }
    soff[8] = acc;
  }
  if (t < 128) {
    cnt[t] = 0;
    sdis[t] = (n0 + t < NN) ? dis[n0 + t] : 0.f;
  }
  __syncthreads();
  int m = soff[8];
#pragma unroll
  for (int x = 0; x < 8; ++x) {
    int c0 = soff[x], c1 = soff[x + 1];
    const unsigned* seg = &pk2[(size_t)((b << 3) | x) * SUBCAP];
    for (int i = c0 + t; i < c1; i += 256) epk[i] = seg[i - c0];
  }
  __syncthreads();
  for (int i = t; i < m; i += 256) atomicAdd(&cnt[epk[i] >> 17], 1);
  __syncthreads();
  if (t < 128) sc[t] = cnt[t];
  __syncthreads();
  for (int o = 1; o < 128; o <<= 1) {
    int u = (t < 128 && t >= o) ? sc[t - o] : 0;
    __syncthreads();
    if (t < 128) sc[t] += u;
    __syncthreads();
  }
  if (t < 128) cur[t] = sc[t] - cnt[t];  // exclusive
  __syncthreads();
  for (int i = t; i < m; i += 256) {
    unsigned p = epk[i];
    int c = (int)(p >> 17);
    int r = (int)(p & 0x1FFFFu);
    int pos = gb + atomicAdd(&cur[c], 1);
    src[pos] = r;
    wh[pos] = (_Float16)(dis[r] * sdis[c]);
  }
}

// convert+transpose conv weights: cw [12][128k][128n] f32 -> wt [12][128n][128k] f16
__global__ void k_wprep(const float* __restrict__ cw, _Float16* __restrict__ wt) {
  int i = blockIdx.x * 256 + threadIdx.x;
  if (i < 12 * 16384) {
    int mat = i >> 14;
    int rem = i & 16383;
    int k = rem >> 7;
    int n = rem & 127;
    wt[(mat << 14) | (n << 7) | k] = (_Float16)cw[i];
  }
}

// last layer fold: uvec[s][k] = sum_n W3_s[k][n]*fcw[n]; cval = cb3.fcw + fcb
__global__ void k_uprep(const float* __restrict__ cw, const float* __restrict__ cb,
                        const float* __restrict__ fcw, const float* __restrict__ fcb,
                        float* __restrict__ uvec, float* __restrict__ cval) {
  int i = blockIdx.x * 256 + threadIdx.x;
  if (i < 512) {
    int s = i >> 7, k = i & 127;
    const float* W = cw + (size_t)(8 + s) * 16384 + k * 128;
    float acc = 0.f;
    for (int n = 0; n < 128; ++n) acc += W[n] * fcw[n];
    uvec[i] = acc;
  }
  if (i == 512) {
    float acc = 0.f;
    for (int n = 0; n < 128; ++n) acc += cb[2 * 128 + n] * fcw[n];
    *cval = acc + fcb[0];
  }
}

// ---------------- propagation ----------------
// fp16 16-wide: 8 lanes per node, 8 nodes per 64-thread block (3.2MB, L2-friendly)
__global__ void k_prop16h(const h2s* __restrict__ h, const int* __restrict__ off,
                          const int* __restrict__ src, const _Float16* __restrict__ wh,
                          h2s* __restrict__ out) {
  int t = threadIdx.x;  // 64
  int node = blockIdx.x * 8 + (t >> 3);
  int f = t & 7;
  int b = off[node], e = off[node + 1];
  float ax = 0.f, ay = 0.f;
  int j = b;
  for (; j + 2 <= e; j += 2) {
    int s0 = src[j], s1 = src[j + 1];
    float w0 = (float)wh[j], w1 = (float)wh[j + 1];
    h2s v0 = h[s0 * 8 + f];
    h2s v1 = h[s1 * 8 + f];
    ax = fmaf((float)v0.x, w0, fmaf((float)v1.x, w1, ax));
    ay = fmaf((float)v0.y, w0, fmaf((float)v1.y, w1, ay));
  }
  if (j < e) {
    int s = src[j];
    float w = (float)wh[j];
    h2s v = h[s * 8 + f];
    ax = fmaf((float)v.x, w, ax);
    ay = fmaf((float)v.y, w, ay);
  }
  h2s o;
  o.x = (_Float16)ax;
  o.y = (_Float16)ay;
  unsigned bits;
  __builtin_memcpy(&bits, &o, 4);
  __builtin_nontemporal_store(bits, (unsigned*)&out[node * 8 + f]);
}

// fp16 128-wide contiguous: one node per WAVE (node wave-uniform so src/wh
// metadata stays on the scalar-load path), 2 waves per 128-thr block.
__global__ __launch_bounds__(128) void k_prop128h(const h2s* __restrict__ h,
                                                  const int* __restrict__ off,
                                                  const int* __restrict__ src,
                                                  const _Float16* __restrict__ wh,
                                                  h2s* __restrict__ out) {
  int wid = __builtin_amdgcn_readfirstlane(threadIdx.x >> 6);
  int node = blockIdx.x * 2 + wid;
  int t = threadIdx.x & 63;
  int b = off[node], e = off[node + 1];
  float ax = 0.f, ay = 0.f;
  int j = b;
  for (; j + 8 <= e; j += 8) {
    h2s v[8];
    float w[8];
#pragma unroll
    for (int u = 0; u < 8; ++u) {
      v[u] = h[src[j + u] * 64 + t];
      w[u] = (float)wh[j + u];
    }
#pragma unroll
    for (int u = 0; u < 8; ++u) {
      ax = fmaf((float)v[u].x, w[u], ax);
      ay = fmaf((float)v[u].y, w[u], ay);
    }
  }
  for (; j < e; ++j) {
    int s = src[j];
    float w = (float)wh[j];
    h2s v = h[s * 64 + t];
    ax = fmaf((float)v.x, w, ax);
    ay = fmaf((float)v.y, w, ay);
  }
  h2s o;
  o.x = (_Float16)ax;
  o.y = (_Float16)ay;
  unsigned bits;
  __builtin_memcpy(&bits, &o, 4);
  __builtin_nontemporal_store(bits, (unsigned*)&out[node * 64 + t]);
}

// ---------------- last-layer rank-1 path: z = h.u_s, scalar propagation ----------------
// Q[n] = {dot(h,u0), dot(h,u1), dot(h,u2), dot(h,u3)}
__global__ void k_dotz(const _Float16* __restrict__ h, const float* __restrict__ uvec,
                       float4* __restrict__ Q) {
  int node = blockIdx.x;
  int t = threadIdx.x;  // 64
  h2s v = ((const h2s*)h)[(size_t)node * 64 + t];
  float p[4];
#pragma unroll
  for (int s = 0; s < 4; ++s) {
    float2 u = ((const float2*)(uvec + (s << 7)))[t];
    p[s] = fmaf((float)v.x, u.x, (float)v.y * u.y);
  }
#pragma unroll
  for (int s = 0; s < 4; ++s)
    for (int o = 32; o; o >>= 1) p[s] += __shfl_down(p[s], o);
  if (t == 0) Q[node] = make_float4(p[0], p[1], p[2], p[3]);
}

// float4 scalar-prop: 4 lanes per node (one component each), 64 nodes per block
__global__ __launch_bounds__(256) void k_zprop(const float* __restrict__ Qin,
                                               const int* __restrict__ off,
                                               const int* __restrict__ src,
                                               const _Float16* __restrict__ wh,
                                               float* __restrict__ Qout) {
  int t = threadIdx.x;
  int node = blockIdx.x * 64 + (t >> 2);
  int comp = t & 3;
  if (node >= NN) return;
  int b = off[node], e = off[node + 1];
  float acc = 0.f;
  int j = b;
  for (; j + 2 <= e; j += 2) {
    int s0 = src[j], s1 = src[j + 1];
    float w0 = (float)wh[j], w1 = (float)wh[j + 1];
    acc = fmaf(Qin[s0 * 4 + comp], w0, fmaf(Qin[s1 * 4 + comp], w1, acc));
  }
  if (j < e) acc = fmaf(Qin[src[j] * 4 + comp], (float)wh[j], acc);
  __builtin_nontemporal_store(acc, &Qout[node * 4 + comp]);
}

// out[n] = Q0.x + (A Q0).y + (A^2 Q0).z + (A^3 Q0).w + cval
__global__ void k_zfinal(const float4* __restrict__ Q0, const float4* __restrict__ Q1,
                         const float4* __restrict__ Q2, const float4* __restrict__ Q3,
                         const float* __restrict__ cval, float* __restrict__ out) {
  int n = blockIdx.x * 256 + threadIdx.x;
  if (n < NN) out[n] = Q0[n].x + Q1[n].y + Q2[n].z + Q3[n].w + *cval;
}

// ---------------- fused TAG layer GEMM (128->128, 4 sources, MFMA f16) ----------------
template <bool RELU>
__global__ __launch_bounds__(256) void k_tag4_mfma(
    const _Float16* __restrict__ A0, const _Float16* __restrict__ A1,
    const _Float16* __restrict__ A2, const _Float16* __restrict__ A3,
    const _Float16* __restrict__ Wt, const float* __restrict__ bias,
    _Float16* __restrict__ out) {
  __shared__ _Float16 Wl[16384];  // 32 KB
  int tid = threadIdx.x;
  int wid = tid >> 6;
  int lane = tid & 63;
  int r = lane & 15, kg = lane >> 4;
  int m0 = blockIdx.x * 128 + wid * 32;
  int row0 = min(m0 + r, NN - 1);
  int row1 = min(m0 + 16 + r, NN - 1);
  f32x4 acc0[8] = {}, acc1[8] = {};
  const _Float16* As[4] = {A0, A1, A2, A3};
#pragma unroll
  for (int s = 0; s < 4; ++s) {
    const float4* Wg = (const float4*)(Wt + (s << 14));  // 2048 granules of 16B
    __syncthreads();
#pragma unroll
    for (int u = 0; u < 8; ++u) {
      int g = tid + u * 256;
      int sg = g ^ ((g >> 4) & 7);
      *(float4*)((char*)Wl + g * 16) = Wg[sg];
    }
    __syncthreads();
    const _Float16* A = As[s];
    half8 a0[4], a1[4];
#pragma unroll
    for (int kc = 0; kc < 4; ++kc) {
      int kbase = kc * 32 + kg * 8;
      a0[kc] = *(const half8*)&A[(size_t)row0 * 128 + kbase];
      a1[kc] = *(const half8*)&A[(size_t)row1 * 128 + kbase];
    }
#pragma unroll
    for (int kc = 0; kc < 4; ++kc) {
      int kb2 = (kc * 32 + kg * 8) * 2;
#pragma unroll
      for (int nb = 0; nb < 8; ++nb) {
        int n = nb * 16 + r;
        int ba = ((n << 8) + kb2) ^ ((n & 7) << 4);
        half8 b = *(const half8*)((const char*)Wl + ba);
        acc0[nb] = __builtin_amdgcn_mfma_f32_16x16x32_f16(a0[kc], b, acc0[nb], 0, 0, 0);
        acc1[nb] = __builtin_amdgcn_mfma_f32_16x16x32_f16(a1[kc], b, acc1[nb], 0, 0, 0);
      }
    }
  }
  int ccol = lane & 15;
#pragma unroll
  for (int h = 0; h < 2; ++h) {
    int crow0 = m0 + h * 16 + kg * 4;
#pragma unroll
    for (int nb = 0; nb < 8; ++nb) {
      int col = nb * 16 + ccol;
      float bv = bias[col];
      const f32x4& av = h ? acc1[nb] : acc0[nb];
#pragma unroll
      for (int e = 0; e < 4; ++e) {
        float v = av[e] + bv;
        if (RELU) v = fmaxf(v, 0.f);
        int rr = crow0 + e;
        if (rr < NN) out[(size_t)rr * 128 + col] = (_Float16)v;
      }
    }
  }
}

// ---------------- conv0 fused (4 fp16 sources 16-wide -> 128, relu, fp16 out) ----------------
__global__ __launch_bounds__(256) void k_conv0_fused(
    const _Float16* __restrict__ A0, const _Float16* __restrict__ A1,
    const _Float16* __restrict__ A2, const _Float16* __restrict__ A3,
    const float* __restrict__ W /*[4][16][128]*/, const float* __restrict__ bias,
    _Float16* __restrict__ out) {
  __shared__ float Wl[4 * 16 * 128];
  for (int i = threadIdx.x * 4; i < 4 * 16 * 128; i += 1024)
    *(float4*)&Wl[i] = *(const float4*)&W[i];
  __syncthreads();
  int r0 = blockIdx.x * 32 + (threadIdx.x >> 5) * 4;
  int c0 = (threadIdx.x & 31) * 4;
  float acc[4][4] = {};
  const _Float16* As[4] = {A0, A1, A2, A3};
#pragma unroll
  for (int s = 0; s < 4; ++s) {
    const _Float16* A = As[s];
    const float* Ws = &Wl[s * 2048];
#pragma unroll
    for (int k = 0; k < 16; k += 4) {
      float4 w0 = *(const float4*)&Ws[(k + 0) * 128 + c0];
      float4 w1 = *(const float4*)&Ws[(k + 1) * 128 + c0];
      float4 w2 = *(const float4*)&Ws[(k + 2) * 128 + c0];
      float4 w3 = *(const float4*)&Ws[(k + 3) * 128 + c0];
#pragma unroll
      for (int i = 0; i < 4; ++i) {
        h4s a4 = *(const h4s*)&A[(r0 + i) * 16 + k];
        float ax = (float)a4.a, ay = (float)a4.b, az = (float)a4.c, aw = (float)a4.d;
        acc[i][0] = fmaf(ax, w0.x, fmaf(ay, w1.x, fmaf(az, w2.x, fmaf(aw, w3.x, acc[i][0]))));
        acc[i][1] = fmaf(ax, w0.y, fmaf(ay, w1.y, fmaf(az, w2.y, fmaf(aw, w3.y, acc[i][1]))));
        acc[i][2] = fmaf(ax, w0.z, fmaf(ay, w1.z, fmaf(az, w2.z, fmaf(aw, w3.z, acc[i][2]))));
        acc[i][3] = fmaf(ax, w0.w, fmaf(ay, w1.w, fmaf(az, w2.w, fmaf(aw, w3.w, acc[i][3]))));
      }
    }
  }
#pragma unroll
  for (int i = 0; i < 4; ++i) {
    h4s o;
    o.a = (_Float16)fmaxf(acc[i][0] + bias[c0 + 0], 0.f);
    o.b = (_Float16)fmaxf(acc[i][1] + bias[c0 + 1], 0.f);
    o.c = (_Float16)fmaxf(acc[i][2] + bias[c0 + 2], 0.f);
    o.d = (_Float16)fmaxf(acc[i][3] + bias[c0 + 3], 0.f);
    *(h4s*)&out[(size_t)(r0 + i) * 128 + c0] = o;
  }
}

// ---------------- feature embedding GEMM (fp32 in, fp16 out, 16 cols) ----------------
template <int IN, bool ACCUM, bool BIAS>
__global__ void k_mm16h(const float* __restrict__ A, const float* __restrict__ W,
                        const float* __restrict__ bias, _Float16* __restrict__ C) {
  __shared__ float Wl[IN * 16];
  for (int i = threadIdx.x; i < IN * 16; i += 256) Wl[i] = W[i];
  __syncthreads();
  int r = blockIdx.x * 16 + (threadIdx.x >> 4);
  int c = threadIdx.x & 15;
  float acc = 0.f;
  for (int k = 0; k < IN; ++k) acc += A[r * IN + k] * Wl[k * 16 + c];
  int idx = r * 16 + c;
  if (BIAS) acc += bias[c];
  if (ACCUM) acc += (float)C[idx];
  C[idx] = (_Float16)acc;
}

extern "C" void kernel_launch(void* const* d_in, const int* in_sizes, int n_in,
                              void* d_out, int out_size, void* d_ws, size_t ws_size,
                              hipStream_t stream) {
  const float* x = (const float*)d_in[0];
  const int* ei = (const int*)d_in[1];
  const float* fe_ws = (const float*)d_in[2];
  const float* fe_b = (const float*)d_in[3];
  const float* c0_ws = (const float*)d_in[4];
  const float* c0_b = (const float*)d_in[5];
  const float* cw = (const float*)d_in[6];
  const float* cb = (const float*)d_in[7];
  const float* fcw = (const float*)d_in[8];
  const float* fcb = (const float*)d_in[9];
  float* out = (float*)d_out;

  const int* row = ei;
  const int* colv = ei + NE;

  char* wp = (char*)d_ws;
  auto alloc = [&](size_t bytes) {
    char* p = wp;
    wp += (bytes + 511) & ~(size_t)511;
    return p;
  };
  int* degi = (int*)alloc(NN * 4);
  int* off = (int*)alloc((NN + 1) * 4);
  int* bsum = (int*)alloc(SCAN_B * 4);
  int* boff = (int*)alloc(SCAN_B * 4);
  int* bcur = (int*)alloc((size_t)NB * 8 * 16 * 4);
  float* dis = (float*)alloc(NN * 4);
  int* src = (int*)alloc((size_t)NE * 4);
  unsigned* pk2 = (unsigned*)alloc((size_t)NB * 8 * SUBCAP * 4);
  _Float16* wh = (_Float16*)alloc((size_t)NE * 2);
  _Float16* wsT = (_Float16*)alloc((size_t)12 * 16384 * 2);
  float* uvec = (float*)alloc(512 * 4);
  float* cval = (float*)alloc(4);
  float4* Q0 = (float4*)alloc((size_t)NN * 16);
  float4* Q1 = (float4*)alloc((size_t)NN * 16);
  float4* Q2 = (float4*)alloc((size_t)NN * 16);
  float4* Q3 = (float4*)alloc((size_t)NN * 16);
  _Float16* y1h = (_Float16*)alloc((size_t)NN * 16 * 2);
  _Float16* h16 = (_Float16*)alloc((size_t)NN * 16 * 2);
  _Float16* p16b = (_Float16*)alloc((size_t)NN * 16 * 2);
  _Float16* p16c = (_Float16*)alloc((size_t)NN * 16 * 2);
  _Float16* p16d = (_Float16*)alloc((size_t)NN * 16 * 2);
  _Float16* H0 = (_Float16*)alloc((size_t)NN * 128 * 2);
  _Float16* H1 = (_Float16*)alloc((size_t)NN * 128 * 2);
  _Float16* T1 = (_Float16*)alloc((size_t)NN * 128 * 2);
  _Float16* T2 = (_Float16*)alloc((size_t)NN * 128 * 2);
  _Float16* T3 = (_Float16*)alloc((size_t)NN * 128 * 2);

  // ---- graph prep ----
  hipMemsetAsync(degi, 0, NN * 4, stream);
  hipMemsetAsync(bcur, 0, (size_t)NB * 8 * 16 * 4, stream);
  k_deg<<<(NE + 255) / 256, 256, 0, stream>>>(colv, degi);
  k_dis<<<(NN + 255) / 256, 256, 0, stream>>>(degi, dis);
  k_scan1<<<SCAN_B, 256, 0, stream>>>(degi, bsum);
  k_scan2<<<1, 128, 0, stream>>>(bsum, boff, off);
  k_scan3<<<SCAN_B, 256, 0, stream>>>(degi, boff, off);
  k_bscatter<<<(NE + 255) / 256, 256, 0, stream>>>(row, colv, bcur, pk2);
  k_bsort<<<NB, 256, 0, stream>>>(pk2, bcur, off, dis, src, wh);
  k_wprep<<<768, 256, 0, stream>>>(cw, wsT);
  k_uprep<<<3, 256, 0, stream>>>(cw, cb, fcw, fcb, uvec, cval);

  // ---- featureEmbedding: h16 = x@W0 + A(x@W1) + b  (prop commutes with W) ----
  k_mm16h<17, false, false><<<NN / 16, 256, 0, stream>>>(x, fe_ws + 17 * 16, nullptr, y1h);
  k_prop16h<<<NN / 8, 64, 0, stream>>>((const h2s*)y1h, off, src, wh, (h2s*)h16);
  k_mm16h<17, true, true><<<NN / 16, 256, 0, stream>>>(x, fe_ws, fe_b, h16);

  // ---- conv0 (16 -> 128, K=3, relu) -> H0 fp16 ----
  k_prop16h<<<NN / 8, 64, 0, stream>>>((const h2s*)h16, off, src, wh, (h2s*)p16b);
  k_prop16h<<<NN / 8, 64, 0, stream>>>((const h2s*)p16b, off, src, wh, (h2s*)p16c);
  k_prop16h<<<NN / 8, 64, 0, stream>>>((const h2s*)p16c, off, src, wh, (h2s*)p16d);
  k_conv0_fused<<<NN / 32, 256, 0, stream>>>(h16, p16b, p16c, p16d, c0_ws, c0_b, H0);

  // ---- conv1..2 (128 -> 128, K=3): 3 props + fused MFMA GEMM each ----
  _Float16* hin = H0;
  _Float16* hout = H1;
  int mgrid = (NN + 127) / 128;
  int pgrid = NN / 2;  // 2 waves per 128-thr block, one node per wave
  for (int l = 0; l < 2; ++l) {
    k_prop128h<<<pgrid, 128, 0, stream>>>((const h2s*)hin, off, src, wh, (h2s*)T1);
    k_prop128h<<<pgrid, 128, 0, stream>>>((const h2s*)T1, off, src, wh, (h2s*)T2);
    k_prop128h<<<pgrid, 128, 0, stream>>>((const h2s*)T2, off, src, wh, (h2s*)T3);
    const _Float16* Wl = wsT + (size_t)l * 4 * 16384;
    const float* bl = cb + l * 128;
    k_tag4_mfma<true><<<mgrid, 256, 0, stream>>>(hin, T1, T2, T3, Wl, bl, hout);
    _Float16* t = hin; hin = hout; hout = t;
  }

  // ---- conv3 + fc, rank-1 folded: z-dots then 3 scalar-quad props ----
  k_dotz<<<NN, 64, 0, stream>>>(hin, uvec, Q0);
  k_zprop<<<(NN + 63) / 64, 256, 0, stream>>>((const float*)Q0, off, src, wh, (float*)Q1);
  k_zprop<<<(NN + 63) / 64, 256, 0, stream>>>((const float*)Q1, off, src, wh, (float*)Q2);
  k_zprop<<<(NN + 63) / 64, 256, 0, stream>>>((const float*)Q2, off, src, wh, (float*)Q3);
  k_zfinal<<<(NN + 255) / 256, 256, 0, stream>>>(Q0, Q1, Q2, Q3, cval, out);
}

// Round 14
// 814.012 us; speedup vs baseline: 1.3103x; 1.0062x over previous
//
#include <hip/hip_runtime.h>

#define NN 100000
#define NE 1600000
#define SCAN_B 98   // 98*1024 >= NN
#define NB 782      // buckets of 128 nodes: 782*128 >= NN
#define SUBCAP 512  // per (bucket,xcd) capacity; mean 256, 512 ~ +16 sigma
#define MAXB 4096   // 8*SUBCAP — guaranteed LDS bound

typedef _Float16 half8 __attribute__((ext_vector_type(8)));
typedef float f32x4 __attribute__((ext_vector_type(4)));
struct h2s { _Float16 x, y; };
struct h4s { _Float16 a, b, c, d; };

// ---------------- graph prep ----------------
__global__ void k_deg(const int* __restrict__ col, int* __restrict__ degi) {
  int e = blockIdx.x * blockDim.x + threadIdx.x;
  if (e < NE) atomicAdd(&degi[col[e]], 1);
}

__global__ void k_dis(const int* __restrict__ degi, float* __restrict__ dis) {
  int i = blockIdx.x * blockDim.x + threadIdx.x;
  if (i < NN) {
    int d = degi[i];
    dis[i] = d > 0 ? rsqrtf((float)d) : 0.0f;
  }
}

__global__ void k_scan1(const int* __restrict__ degi, int* __restrict__ bsum) {
  __shared__ int red[256];
  int t = threadIdx.x;
  int base = blockIdx.x * 1024 + t * 4;
  int s = 0;
#pragma unroll
  for (int u = 0; u < 4; ++u) {
    int i = base + u;
    if (i < NN) s += degi[i];
  }
  red[t] = s;
  __syncthreads();
  for (int o = 128; o; o >>= 1) {
    if (t < o) red[t] += red[t + o];
    __syncthreads();
  }
  if (t == 0) bsum[blockIdx.x] = red[0];
}

__global__ void k_scan2(const int* __restrict__ bsum, int* __restrict__ boff,
                        int* __restrict__ off) {
  __shared__ int sh[128];
  int t = threadIdx.x;  // 128
  int v = (t < SCAN_B) ? bsum[t] : 0;
  sh[t] = v;
  __syncthreads();
  for (int o = 1; o < 128; o <<= 1) {
    int u = (t >= o) ? sh[t - o] : 0;
    __syncthreads();
    sh[t] += u;
    __syncthreads();
  }
  if (t < SCAN_B) boff[t] = sh[t] - v;
  if (t == 127) off[NN] = sh[127];
}

__global__ void k_scan3(const int* __restrict__ degi, const int* __restrict__ boff,
                        int* __restrict__ off) {
  __shared__ int red[256];
  int t = threadIdx.x;
  int base = blockIdx.x * 1024 + t * 4;
  int d[4];
  int s = 0;
#pragma unroll
  for (int u = 0; u < 4; ++u) {
    int i = base + u;
    d[u] = (i < NN) ? degi[i] : 0;
    s += d[u];
  }
  red[t] = s;
  __syncthreads();
  for (int o = 1; o < 256; o <<= 1) {
    int u2 = (t >= o) ? red[t - o] : 0;
    __syncthreads();
    red[t] += u2;
    __syncthreads();
  }
  int pre = red[t] - s + boff[blockIdx.x];
#pragma unroll
  for (int u = 0; u < 4; ++u) {
    int i = base + u;
    if (i < NN) {
      off[i] = pre;
      pre += d[u];
    }
  }
}

// Phase B: scatter packed {row, col&127} into per-(bucket,XCD) sub-buckets.
// NT loads on the edge streams reduce L2 eviction of the write-front lines.
__global__ void k_bscatter(const int* __restrict__ row, const int* __restrict__ col,
                           int* __restrict__ bcur, unsigned* __restrict__ pk2) {
  int e = blockIdx.x * blockDim.x + threadIdx.x;
  int x = blockIdx.x & 7;
  if (e < NE) {
    int c = __builtin_nontemporal_load(&col[e]);
    int r = __builtin_nontemporal_load(&row[e]);
    int cell = ((c >> 7) << 3) | x;
    int slot = atomicAdd(&bcur[cell * 16], 1);
    slot = min(slot, SUBCAP - 1);  // statistically unreachable (16 sigma)
    pk2[(size_t)cell * SUBCAP + slot] = (unsigned)r | ((unsigned)(c & 127) << 17);
  }
}

// Phase C: per-bucket LDS counting sort over 8 sub-segments -> sequential src+wh
__global__ __launch_bounds__(256) void k_bsort(const unsigned* __restrict__ pk2,
                                               const int* __restrict__ bcur,
                                               const int* __restrict__ off,
                                               const float* __restrict__ dis,
                                               int* __restrict__ src,
                                               _Float16* __restrict__ wh) {
  __shared__ unsigned epk[MAXB];
  __shared__ int cnt[128];
  __shared__ int sc[128];
  __shared__ int cur[128];
  __shared__ float sdis[128];
  __shared__ int soff[9];
  int b = blockIdx.x;
  int n0 = b << 7;
  int gb = off[n0];
  int t = threadIdx.x;
  if (t == 0) {
    int acc = 0;
#pragma unroll
    for (int x = 0; x < 8; ++x) {
      soff[x] = acc;
      acc += min(bcur[((b << 3) | x) * 16], SUBCAP);
    }
    soff[8] = acc;
  }
  if (t < 128) {
    cnt[t] = 0;
    sdis[t] = (n0 + t < NN) ? dis[n0 + t] : 0.f;
  }
  __syncthreads();
  int m = soff[8];
#pragma unroll
  for (int x = 0; x < 8; ++x) {
    int c0 = soff[x], c1 = soff[x + 1];
    const unsigned* seg = &pk2[(size_t)((b << 3) | x) * SUBCAP];
    for (int i = c0 + t; i < c1; i += 256) epk[i] = seg[i - c0];
  }
  __syncthreads();
  for (int i = t; i < m; i += 256) atomicAdd(&cnt[epk[i] >> 17], 1);
  __syncthreads();
  if (t < 128) sc[t] = cnt[t];
  __syncthreads();
  for (int o = 1; o < 128; o <<= 1) {
    int u = (t < 128 && t >= o) ? sc[t - o] : 0;
    __syncthreads();
    if (t < 128) sc[t] += u;
    __syncthreads();
  }
  if (t < 128) cur[t] = sc[t] - cnt[t];  // exclusive
  __syncthreads();
  for (int i = t; i < m; i += 256) {
    unsigned p = epk[i];
    int c = (int)(p >> 17);
    int r = (int)(p & 0x1FFFFu);
    int pos = gb + atomicAdd(&cur[c], 1);
    src[pos] = r;
    wh[pos] = (_Float16)(dis[r] * sdis[c]);
  }
}

// convert+transpose conv weights: cw [12][128k][128n] f32 -> wt [12][128n][128k] f16
__global__ void k_wprep(const float* __restrict__ cw, _Float16* __restrict__ wt) {
  int i = blockIdx.x * 256 + threadIdx.x;
  if (i < 12 * 16384) {
    int mat = i >> 14;
    int rem = i & 16383;
    int k = rem >> 7;
    int n = rem & 127;
    wt[(mat << 14) | (n << 7) | k] = (_Float16)cw[i];
  }
}

// last layer fold: uvec[s][k] = sum_n W3_s[k][n]*fcw[n]; cval = cb3.fcw + fcb
__global__ void k_uprep(const float* __restrict__ cw, const float* __restrict__ cb,
                        const float* __restrict__ fcw, const float* __restrict__ fcb,
                        float* __restrict__ uvec, float* __restrict__ cval) {
  int i = blockIdx.x * 256 + threadIdx.x;
  if (i < 512) {
    int s = i >> 7, k = i & 127;
    const float* W = cw + (size_t)(8 + s) * 16384 + k * 128;
    float acc = 0.f;
    for (int n = 0; n < 128; ++n) acc += W[n] * fcw[n];
    uvec[i] = acc;
  }
  if (i == 512) {
    float acc = 0.f;
    for (int n = 0; n < 128; ++n) acc += cb[2 * 128 + n] * fcw[n];
    *cval = acc + fcb[0];
  }
}

// ---------------- propagation ----------------
// fp16 16-wide: 8 lanes per node, 8 nodes per 64-thread block (3.2MB, L2-friendly)
__global__ void k_prop16h(const h2s* __restrict__ h, const int* __restrict__ off,
                          const int* __restrict__ src, const _Float16* __restrict__ wh,
                          h2s* __restrict__ out) {
  int t = threadIdx.x;  // 64
  int node = blockIdx.x * 8 + (t >> 3);
  int f = t & 7;
  int b = off[node], e = off[node + 1];
  float ax = 0.f, ay = 0.f;
  int j = b;
  for (; j + 2 <= e; j += 2) {
    int s0 = src[j], s1 = src[j + 1];
    float w0 = (float)wh[j], w1 = (float)wh[j + 1];
    h2s v0 = h[s0 * 8 + f];
    h2s v1 = h[s1 * 8 + f];
    ax = fmaf((float)v0.x, w0, fmaf((float)v1.x, w1, ax));
    ay = fmaf((float)v0.y, w0, fmaf((float)v1.y, w1, ay));
  }
  if (j < e) {
    int s = src[j];
    float w = (float)wh[j];
    h2s v = h[s * 8 + f];
    ax = fmaf((float)v.x, w, ax);
    ay = fmaf((float)v.y, w, ay);
  }
  h2s o;
  o.x = (_Float16)ax;
  o.y = (_Float16)ay;
  unsigned bits;
  __builtin_memcpy(&bits, &o, 4);
  __builtin_nontemporal_store(bits, (unsigned*)&out[node * 8 + f]);
}

// fp16 128-wide, paired-edge gather: 32 lanes x 8B per row, one gather instr
// covers TWO edges (half = lane>>5). Metadata stays scalar + cndmask select.
// One node per wave, 2 waves per 128-thr block.
__global__ __launch_bounds__(128) void k_prop128h(const h2s* __restrict__ h,
                                                  const int* __restrict__ off,
                                                  const int* __restrict__ src,
                                                  const _Float16* __restrict__ wh,
                                                  h2s* __restrict__ out) {
  int wid = __builtin_amdgcn_readfirstlane(threadIdx.x >> 6);
  int node = blockIdx.x * 2 + wid;
  int t = threadIdx.x & 63;
  int half = t >> 5;
  int fl = t & 31;  // feature quad: feats 4*fl..4*fl+3
  const h4s* hp = (const h4s*)h;  // row = 32 h4s = 256B
  int b = off[node], e = off[node + 1];
  float a0 = 0.f, a1 = 0.f, a2 = 0.f, a3 = 0.f;
  int j = b;
  for (; j + 8 <= e; j += 8) {
    h4s v[4];
    float w[4];
#pragma unroll
    for (int u = 0; u < 4; ++u) {
      int s0 = src[j + 2 * u];
      int s1 = src[j + 2 * u + 1];
      float w0 = (float)wh[j + 2 * u];
      float w1 = (float)wh[j + 2 * u + 1];
      int s = half ? s1 : s0;
      w[u] = half ? w1 : w0;
      v[u] = hp[(size_t)s * 32 + fl];
    }
#pragma unroll
    for (int u = 0; u < 4; ++u) {
      a0 = fmaf((float)v[u].a, w[u], a0);
      a1 = fmaf((float)v[u].b, w[u], a1);
      a2 = fmaf((float)v[u].c, w[u], a2);
      a3 = fmaf((float)v[u].d, w[u], a3);
    }
  }
  for (; j + 2 <= e; j += 2) {
    int s0 = src[j], s1 = src[j + 1];
    float w0 = (float)wh[j], w1 = (float)wh[j + 1];
    int s = half ? s1 : s0;
    float w = half ? w1 : w0;
    h4s v = hp[(size_t)s * 32 + fl];
    a0 = fmaf((float)v.a, w, a0);
    a1 = fmaf((float)v.b, w, a1);
    a2 = fmaf((float)v.c, w, a2);
    a3 = fmaf((float)v.d, w, a3);
  }
  if (j < e) {  // single tail edge: half==0 lanes only
    int s = src[j];
    float w = (float)wh[j];
    if (half == 0) {
      h4s v = hp[(size_t)s * 32 + fl];
      a0 = fmaf((float)v.a, w, a0);
      a1 = fmaf((float)v.b, w, a1);
      a2 = fmaf((float)v.c, w, a2);
      a3 = fmaf((float)v.d, w, a3);
    }
  }
  a0 += __shfl_xor(a0, 32);
  a1 += __shfl_xor(a1, 32);
  a2 += __shfl_xor(a2, 32);
  a3 += __shfl_xor(a3, 32);
  if (half == 0) {
    h4s o;
    o.a = (_Float16)a0;
    o.b = (_Float16)a1;
    o.c = (_Float16)a2;
    o.d = (_Float16)a3;
    unsigned long long bits;
    __builtin_memcpy(&bits, &o, 8);
    __builtin_nontemporal_store(bits, (unsigned long long*)&((h4s*)out)[(size_t)node * 32 + fl]);
  }
}

// ---------------- last-layer rank-1 path: z = h.u_s, scalar propagation ----------------
__global__ void k_dotz(const _Float16* __restrict__ h, const float* __restrict__ uvec,
                       float4* __restrict__ Q) {
  int node = blockIdx.x;
  int t = threadIdx.x;  // 64
  h2s v = ((const h2s*)h)[(size_t)node * 64 + t];
  float p[4];
#pragma unroll
  for (int s = 0; s < 4; ++s) {
    float2 u = ((const float2*)(uvec + (s << 7)))[t];
    p[s] = fmaf((float)v.x, u.x, (float)v.y * u.y);
  }
#pragma unroll
  for (int s = 0; s < 4; ++s)
    for (int o = 32; o; o >>= 1) p[s] += __shfl_down(p[s], o);
  if (t == 0) Q[node] = make_float4(p[0], p[1], p[2], p[3]);
}

__global__ __launch_bounds__(256) void k_zprop(const float* __restrict__ Qin,
                                               const int* __restrict__ off,
                                               const int* __restrict__ src,
                                               const _Float16* __restrict__ wh,
                                               float* __restrict__ Qout) {
  int t = threadIdx.x;
  int node = blockIdx.x * 64 + (t >> 2);
  int comp = t & 3;
  if (node >= NN) return;
  int b = off[node], e = off[node + 1];
  float acc = 0.f;
  int j = b;
  for (; j + 2 <= e; j += 2) {
    int s0 = src[j], s1 = src[j + 1];
    float w0 = (float)wh[j], w1 = (float)wh[j + 1];
    acc = fmaf(Qin[s0 * 4 + comp], w0, fmaf(Qin[s1 * 4 + comp], w1, acc));
  }
  if (j < e) acc = fmaf(Qin[src[j] * 4 + comp], (float)wh[j], acc);
  __builtin_nontemporal_store(acc, &Qout[node * 4 + comp]);
}

__global__ void k_zfinal(const float4* __restrict__ Q0, const float4* __restrict__ Q1,
                         const float4* __restrict__ Q2, const float4* __restrict__ Q3,
                         const float* __restrict__ cval, float* __restrict__ out) {
  int n = blockIdx.x * 256 + threadIdx.x;
  if (n < NN) out[n] = Q0[n].x + Q1[n].y + Q2[n].z + Q3[n].w + *cval;
}

// ---------------- fused TAG layer GEMM (128->128, 4 sources, MFMA f16) ----------------
template <bool RELU>
__global__ __launch_bounds__(256) void k_tag4_mfma(
    const _Float16* __restrict__ A0, const _Float16* __restrict__ A1,
    const _Float16* __restrict__ A2, const _Float16* __restrict__ A3,
    const _Float16* __restrict__ Wt, const float* __restrict__ bias,
    _Float16* __restrict__ out) {
  __shared__ _Float16 Wl[16384];  // 32 KB
  int tid = threadIdx.x;
  int wid = tid >> 6;
  int lane = tid & 63;
  int r = lane & 15, kg = lane >> 4;
  int m0 = blockIdx.x * 128 + wid * 32;
  int row0 = min(m0 + r, NN - 1);
  int row1 = min(m0 + 16 + r, NN - 1);
  f32x4 acc0[8] = {}, acc1[8] = {};
  const _Float16* As[4] = {A0, A1, A2, A3};
#pragma unroll
  for (int s = 0; s < 4; ++s) {
    const float4* Wg = (const float4*)(Wt + (s << 14));  // 2048 granules of 16B
    __syncthreads();
#pragma unroll
    for (int u = 0; u < 8; ++u) {
      int g = tid + u * 256;
      int sg = g ^ ((g >> 4) & 7);
      *(float4*)((char*)Wl + g * 16) = Wg[sg];
    }
    __syncthreads();
    const _Float16* A = As[s];
    half8 a0[4], a1[4];
#pragma unroll
    for (int kc = 0; kc < 4; ++kc) {
      int kbase = kc * 32 + kg * 8;
      a0[kc] = *(const half8*)&A[(size_t)row0 * 128 + kbase];
      a1[kc] = *(const half8*)&A[(size_t)row1 * 128 + kbase];
    }
#pragma unroll
    for (int kc = 0; kc < 4; ++kc) {
      int kb2 = (kc * 32 + kg * 8) * 2;
#pragma unroll
      for (int nb = 0; nb < 8; ++nb) {
        int n = nb * 16 + r;
        int ba = ((n << 8) + kb2) ^ ((n & 7) << 4);
        half8 b = *(const half8*)((const char*)Wl + ba);
        acc0[nb] = __builtin_amdgcn_mfma_f32_16x16x32_f16(a0[kc], b, acc0[nb], 0, 0, 0);
        acc1[nb] = __builtin_amdgcn_mfma_f32_16x16x32_f16(a1[kc], b, acc1[nb], 0, 0, 0);
      }
    }
  }
  int ccol = lane & 15;
#pragma unroll
  for (int h = 0; h < 2; ++h) {
    int crow0 = m0 + h * 16 + kg * 4;
#pragma unroll
    for (int nb = 0; nb < 8; ++nb) {
      int col = nb * 16 + ccol;
      float bv = bias[col];
      const f32x4& av = h ? acc1[nb] : acc0[nb];
#pragma unroll
      for (int e = 0; e < 4; ++e) {
        float v = av[e] + bv;
        if (RELU) v = fmaxf(v, 0.f);
        int rr = crow0 + e;
        if (rr < NN) out[(size_t)rr * 128 + col] = (_Float16)v;
      }
    }
  }
}

// ---------------- conv0 fused (4 fp16 sources 16-wide -> 128, relu, fp16 out) ----------------
__global__ __launch_bounds__(256) void k_conv0_fused(
    const _Float16* __restrict__ A0, const _Float16* __restrict__ A1,
    const _Float16* __restrict__ A2, const _Float16* __restrict__ A3,
    const float* __restrict__ W /*[4][16][128]*/, const float* __restrict__ bias,
    _Float16* __restrict__ out) {
  __shared__ float Wl[4 * 16 * 128];
  for (int i = threadIdx.x * 4; i < 4 * 16 * 128; i += 1024)
    *(float4*)&Wl[i] = *(const float4*)&W[i];
  __syncthreads();
  int r0 = blockIdx.x * 32 + (threadIdx.x >> 5) * 4;
  int c0 = (threadIdx.x & 31) * 4;
  float acc[4][4] = {};
  const _Float16* As[4] = {A0, A1, A2, A3};
#pragma unroll
  for (int s = 0; s < 4; ++s) {
    const _Float16* A = As[s];
    const float* Ws = &Wl[s * 2048];
#pragma unroll
    for (int k = 0; k < 16; k += 4) {
      float4 w0 = *(const float4*)&Ws[(k + 0) * 128 + c0];
      float4 w1 = *(const float4*)&Ws[(k + 1) * 128 + c0];
      float4 w2 = *(const float4*)&Ws[(k + 2) * 128 + c0];
      float4 w3 = *(const float4*)&Ws[(k + 3) * 128 + c0];
#pragma unroll
      for (int i = 0; i < 4; ++i) {
        h4s a4 = *(const h4s*)&A[(r0 + i) * 16 + k];
        float ax = (float)a4.a, ay = (float)a4.b, az = (float)a4.c, aw = (float)a4.d;
        acc[i][0] = fmaf(ax, w0.x, fmaf(ay, w1.x, fmaf(az, w2.x, fmaf(aw, w3.x, acc[i][0]))));
        acc[i][1] = fmaf(ax, w0.y, fmaf(ay, w1.y, fmaf(az, w2.y, fmaf(aw, w3.y, acc[i][1]))));
        acc[i][2] = fmaf(ax, w0.z, fmaf(ay, w1.z, fmaf(az, w2.z, fmaf(aw, w3.z, acc[i][2]))));
        acc[i][3] = fmaf(ax, w0.w, fmaf(ay, w1.w, fmaf(az, w2.w, fmaf(aw, w3.w, acc[i][3]))));
      }
    }
  }
#pragma unroll
  for (int i = 0; i < 4; ++i) {
    h4s o;
    o.a = (_Float16)fmaxf(acc[i][0] + bias[c0 + 0], 0.f);
    o.b = (_Float16)fmaxf(acc[i][1] + bias[c0 + 1], 0.f);
    o.c = (_Float16)fmaxf(acc[i][2] + bias[c0 + 2], 0.f);
    o.d = (_Float16)fmaxf(acc[i][3] + bias[c0 + 3], 0.f);
    *(h4s*)&out[(size_t)(r0 + i) * 128 + c0] = o;
  }
}

// ---------------- feature embedding GEMM (fp32 in, fp16 out, 16 cols) ----------------
template <int IN, bool ACCUM, bool BIAS>
__global__ void k_mm16h(const float* __restrict__ A, const float* __restrict__ W,
                        const float* __restrict__ bias, _Float16* __restrict__ C) {
  __shared__ float Wl[IN * 16];
  for (int i = threadIdx.x; i < IN * 16; i += 256) Wl[i] = W[i];
  __syncthreads();
  int r = blockIdx.x * 16 + (threadIdx.x >> 4);
  int c = threadIdx.x & 15;
  float acc = 0.f;
  for (int k = 0; k < IN; ++k) acc += A[r * IN + k] * Wl[k * 16 + c];
  int idx = r * 16 + c;
  if (BIAS) acc += bias[c];
  if (ACCUM) acc += (float)C[idx];
  C[idx] = (_Float16)acc;
}

extern "C" void kernel_launch(void* const* d_in, const int* in_sizes, int n_in,
                              void* d_out, int out_size, void* d_ws, size_t ws_size,
                              hipStream_t stream) {
  const float* x = (const float*)d_in[0];
  const int* ei = (const int*)d_in[1];
  const float* fe_ws = (const float*)d_in[2];
  const float* fe_b = (const float*)d_in[3];
  const float* c0_ws = (const float*)d_in[4];
  const float* c0_b = (const float*)d_in[5];
  const float* cw = (const float*)d_in[6];
  const float* cb = (const float*)d_in[7];
  const float* fcw = (const float*)d_in[8];
  const float* fcb = (const float*)d_in[9];
  float* out = (float*)d_out;

  const int* row = ei;
  const int* colv = ei + NE;

  char* wp = (char*)d_ws;
  auto alloc = [&](size_t bytes) {
    char* p = wp;
    wp += (bytes + 511) & ~(size_t)511;
    return p;
  };
  int* degi = (int*)alloc(NN * 4);
  int* off = (int*)alloc((NN + 1) * 4);
  int* bsum = (int*)alloc(SCAN_B * 4);
  int* boff = (int*)alloc(SCAN_B * 4);
  int* bcur = (int*)alloc((size_t)NB * 8 * 16 * 4);
  float* dis = (float*)alloc(NN * 4);
  int* src = (int*)alloc((size_t)NE * 4);
  unsigned* pk2 = (unsigned*)alloc((size_t)NB * 8 * SUBCAP * 4);
  _Float16* wh = (_Float16*)alloc((size_t)NE * 2);
  _Float16* wsT = (_Float16*)alloc((size_t)12 * 16384 * 2);
  float* uvec = (float*)alloc(512 * 4);
  float* cval = (float*)alloc(4);
  float4* Q0 = (float4*)alloc((size_t)NN * 16);
  float4* Q1 = (float4*)alloc((size_t)NN * 16);
  float4* Q2 = (float4*)alloc((size_t)NN * 16);
  float4* Q3 = (float4*)alloc((size_t)NN * 16);
  _Float16* y1h = (_Float16*)alloc((size_t)NN * 16 * 2);
  _Float16* h16 = (_Float16*)alloc((size_t)NN * 16 * 2);
  _Float16* p16b = (_Float16*)alloc((size_t)NN * 16 * 2);
  _Float16* p16c = (_Float16*)alloc((size_t)NN * 16 * 2);
  _Float16* p16d = (_Float16*)alloc((size_t)NN * 16 * 2);
  _Float16* H0 = (_Float16*)alloc((size_t)NN * 128 * 2);
  _Float16* H1 = (_Float16*)alloc((size_t)NN * 128 * 2);
  _Float16* T1 = (_Float16*)alloc((size_t)NN * 128 * 2);
  _Float16* T2 = (_Float16*)alloc((size_t)NN * 128 * 2);
  _Float16* T3 = (_Float16*)alloc((size_t)NN * 128 * 2);

  // ---- graph prep ----
  hipMemsetAsync(degi, 0, NN * 4, stream);
  hipMemsetAsync(bcur, 0, (size_t)NB * 8 * 16 * 4, stream);
  k_deg<<<(NE + 255) / 256, 256, 0, stream>>>(colv, degi);
  k_dis<<<(NN + 255) / 256, 256, 0, stream>>>(degi, dis);
  k_scan1<<<SCAN_B, 256, 0, stream>>>(degi, bsum);
  k_scan2<<<1, 128, 0, stream>>>(bsum, boff, off);
  k_scan3<<<SCAN_B, 256, 0, stream>>>(degi, boff, off);
  k_bscatter<<<(NE + 255) / 256, 256, 0, stream>>>(row, colv, bcur, pk2);
  k_bsort<<<NB, 256, 0, stream>>>(pk2, bcur, off, dis, src, wh);
  k_wprep<<<768, 256, 0, stream>>>(cw, wsT);
  k_uprep<<<3, 256, 0, stream>>>(cw, cb, fcw, fcb, uvec, cval);

  // ---- featureEmbedding: h16 = x@W0 + A(x@W1) + b  (prop commutes with W) ----
  k_mm16h<17, false, false><<<NN / 16, 256, 0, stream>>>(x, fe_ws + 17 * 16, nullptr, y1h);
  k_prop16h<<<NN / 8, 64, 0, stream>>>((const h2s*)y1h, off, src, wh, (h2s*)h16);
  k_mm16h<17, true, true><<<NN / 16, 256, 0, stream>>>(x, fe_ws, fe_b, h16);

  // ---- conv0 (16 -> 128, K=3, relu) -> H0 fp16 ----
  k_prop16h<<<NN / 8, 64, 0, stream>>>((const h2s*)h16, off, src, wh, (h2s*)p16b);
  k_prop16h<<<NN / 8, 64, 0, stream>>>((const h2s*)p16b, off, src, wh, (h2s*)p16c);
  k_prop16h<<<NN / 8, 64, 0, stream>>>((const h2s*)p16c, off, src, wh, (h2s*)p16d);
  k_conv0_fused<<<NN / 32, 256, 0, stream>>>(h16, p16b, p16c, p16d, c0_ws, c0_b, H0);

  // ---- conv1..2 (128 -> 128, K=3): 3 props + fused MFMA GEMM each ----
  _Float16* hin = H0;
  _Float16* hout = H1;
  int mgrid = (NN + 127) / 128;
  int pgrid = NN / 2;  // 2 waves per 128-thr block, one node per wave
  for (int l = 0; l < 2; ++l) {
    k_prop128h<<<pgrid, 128, 0, stream>>>((const h2s*)hin, off, src, wh, (h2s*)T1);
    k_prop128h<<<pgrid, 128, 0, stream>>>((const h2s*)T1, off, src, wh, (h2s*)T2);
    k_prop128h<<<pgrid, 128, 0, stream>>>((const h2s*)T2, off, src, wh, (h2s*)T3);
    const _Float16* Wl = wsT + (size_t)l * 4 * 16384;
    const float* bl = cb + l * 128;
    k_tag4_mfma<true><<<mgrid, 256, 0, stream>>>(hin, T1, T2, T3, Wl, bl, hout);
    _Float16* t = hin; hin = hout; hout = t;
  }

  // ---- conv3 + fc, rank-1 folded: z-dots then 3 scalar-quad props ----
  k_dotz<<<NN, 64, 0, stream>>>(hin, uvec, Q0);
  k_zprop<<<(NN + 63) / 64, 256, 0, stream>>>((const float*)Q0, off, src, wh, (float*)Q1);
  k_zprop<<<(NN + 63) / 64, 256, 0, stream>>>((const float*)Q1, off, src, wh, (float*)Q2);
  k_zprop<<<(NN + 63) / 64, 256, 0, stream>>>((const float*)Q2, off, src, wh, (float*)Q3);
  k_zfinal<<<(NN + 255) / 256, 256, 0, stream>>>(Q0, Q1, Q2, Q3, cval, out);
}